// Round 9
// baseline (489.177 us; speedup 1.0000x reference)
//
#include <hip/hip_runtime.h>
#include <math.h>

#define BB 8
#define PP 57744
#define NOBJ 20
#define CC 81
#define ROWS (BB*PP)
#define RPB 64        // rows per block in k_conf (proven 159us structure)
#define BPSPLIT 16
#define BPCHUNK ((PP + BPSPLIT - 1) / BPSPLIT)   // 3609
#define HISTBLK 512
#define NEGBLK 512

// ws layout in 4-byte units
// cnt: [0]=num_pos [1]=sl1_sum(f) [2]=pos_ce(f) [3]=neg_ce(f) [4]=neg_cnt
//      [5]=eqCtr [13]=negsum_done
#define W_CNT  0                        // 64 words
#define W_HA   64                       // 8 copies x 2048 bins (bits 31:21)
#define W_HB   (W_HA + 8*2048)          // 8 copies x 2048 (bits 20:10)
#define W_HC   (W_HB + 8*2048)          // 8 copies x 1024 (bits 9:0)
#define W_BP   (W_HC + 8*1024)          // word 41024 (byte 164096, 8-aligned)
#define W_CONF (W_BP + 320)             // ROWS ints
#define W_KEY  (W_CONF + ROWS)          // ROWS uints
#define W_CE   (W_KEY + ROWS)           // ROWS floats
#define MEMSET_BYTES (W_CONF * 4)       // counters + hists + bp

#define SCOPE_AGENT __HIP_MEMORY_SCOPE_AGENT
// Completion ordering only (no buffer_wbl2/buffer_inv cache maintenance —
// the round-5 410us lesson): prior vmem ops retired at the coherence point.
#define VMEM_DRAIN() asm volatile("s_waitcnt vmcnt(0) lgkmcnt(0)" ::: "memory")

__device__ __forceinline__ unsigned keymap(float f) {
    unsigned u = __float_as_uint(f);
    return (u & 0x80000000u) ? ~u : (u | 0x80000000u);
}

__device__ __forceinline__ float smooth_l1(float d) {
    float a = fabsf(d);
    return a < 1.f ? 0.5f * d * d : a - 0.5f;
}

__device__ __forceinline__ unsigned aload_u(const unsigned* p) {
    return __hip_atomic_load(p, __ATOMIC_RELAXED, SCOPE_AGENT);
}
__device__ __forceinline__ int aload_i(const int* p) {
    return __hip_atomic_load(p, __ATOMIC_RELAXED, SCOPE_AGENT);
}
__device__ __forceinline__ float aload_f(const float* p) {
    return __hip_atomic_load(p, __ATOMIC_RELAXED, SCOPE_AGENT);
}

// Descending-cumulative threshold search over NB bins summed across 8 global
// copies. Finds bin with suffix(bin) >= Kr && suffix(bin+1) < Kr; *rem_out =
// Kr - suffix(bin+1). Returns -1 if total < Kr. Whole block participates;
// deterministic given identical inputs, so every block may recompute it
// redundantly (replaces single-block scan launches; no grid sync needed —
// the previous kernel's boundary makes its hist writes coherent).
template <int NB>
__device__ int scan_bins(const unsigned* h, unsigned Kr, unsigned* rem_out) {
    constexpr int BPT = NB / 256;
    __shared__ unsigned stot[256];
    __shared__ int sbin;
    __shared__ unsigned srem;
    __syncthreads();                 // protect shared reuse across calls
    int i = threadIdx.x;
    unsigned v[BPT];
    unsigned tot = 0;
    #pragma unroll
    for (int j = 0; j < BPT; j++) {
        unsigned s = 0;
        #pragma unroll
        for (int c = 0; c < 8; c++) s += aload_u(h + c * NB + i * BPT + j);
        v[j] = s; tot += s;
    }
    if (i == 0) sbin = -1;
    stot[i] = tot; __syncthreads();
    for (int off = 1; off < 256; off <<= 1) {   // inclusive suffix scan
        unsigned add = (i + off < 256) ? stot[i + off] : 0u;
        __syncthreads(); stot[i] += add; __syncthreads();
    }
    unsigned cum = (i < 255) ? stot[i + 1] : 0u;   // suffix of threads > i
    #pragma unroll
    for (int j = BPT - 1; j >= 0; j--) {
        unsigned nxt = cum;      // suffix(bin+1)
        cum += v[j];             // suffix(bin)
        if (cum >= Kr && nxt < Kr) { sbin = i * BPT + j; srem = Kr - nxt; }
    }
    __syncthreads();
    *rem_out = (sbin >= 0) ? srem : 0u;
    return sbin;
}

// Grid (NOBJ, BB, BPSPLIT): per-(gt,batch) argmax over a prior chunk, packed
// (iou_bits<<32)|(~p) so u64 max == (max iou, lowest prior idx).
__global__ void k_best_prior(const float* __restrict__ priors,
                             const float* __restrict__ gt,
                             unsigned long long* __restrict__ bp) {
    int n = blockIdx.x, b = blockIdx.y;
    int p0 = blockIdx.z * BPCHUNK;
    int p1 = min(p0 + BPCHUNK, PP);
    const float* t = gt + (b * NOBJ + n) * 4;
    float tx1 = t[0], ty1 = t[1], tx2 = t[2], ty2 = t[3];
    float ta = (tx2 - tx1) * (ty2 - ty1);
    unsigned long long best = 0ull;
    for (int p = p0 + threadIdx.x; p < p1; p += 256) {
        float4 pr = ((const float4*)priors)[p];
        float px1 = pr.x - pr.z * 0.5f, py1 = pr.y - pr.w * 0.5f;
        float px2 = pr.x + pr.z * 0.5f, py2 = pr.y + pr.w * 0.5f;
        float iw = fmaxf(fminf(tx2, px2) - fmaxf(tx1, px1), 0.f);
        float ih = fmaxf(fminf(ty2, py2) - fmaxf(ty1, py1), 0.f);
        float inter = iw * ih;
        float iou = inter / (ta + (px2 - px1) * (py2 - py1) - inter);
        unsigned long long pk = ((unsigned long long)__float_as_uint(iou) << 32)
                              | (unsigned long long)(0xFFFFFFFFu - (unsigned)p);
        if (pk > best) best = pk;
    }
    __shared__ unsigned long long sb[256];
    int tid = threadIdx.x;
    sb[tid] = best; __syncthreads();
    for (int s = 128; s > 0; s >>= 1) {
        if (tid < s && sb[tid + s] > sb[tid]) sb[tid] = sb[tid + s];
        __syncthreads();
    }
    if (tid == 0) atomicMax(&bp[b * NOBJ + n], sb[0]);
}

// Per prior: best truth (argmax over 20, tie->first), force-match (last gt wins),
// conf_t, and smooth-L1 loc loss for positives.
__global__ void k_match(const float* __restrict__ loc_data,
                        const float* __restrict__ priors,
                        const float* __restrict__ gt,
                        const int* __restrict__ labels,
                        const unsigned long long* __restrict__ bp,
                        int* __restrict__ conf_t,
                        float* __restrict__ cnt_f,
                        int* __restrict__ cnt_i) {
    int b = blockIdx.y;
    int tid = threadIdx.x;
    int p = blockIdx.x * 256 + tid;
    __shared__ float st[NOBJ][4];
    __shared__ int slab[NOBJ], sbp[NOBJ];
    if (tid < NOBJ * 4) ((float*)st)[tid] = gt[b * NOBJ * 4 + tid];
    if (tid < NOBJ) {
        slab[tid] = labels[b * NOBJ + tid];
        sbp[tid] = (int)(0xFFFFFFFFu - (unsigned)bp[b * NOBJ + tid]);
    }
    __syncthreads();
    float s_l1 = 0.f; int is_pos = 0;
    if (p < PP) {
        float4 pr = ((const float4*)priors)[p];
        float px1 = pr.x - pr.z * 0.5f, py1 = pr.y - pr.w * 0.5f;
        float px2 = pr.x + pr.z * 0.5f, py2 = pr.y + pr.w * 0.5f;
        float pa = (px2 - px1) * (py2 - py1);
        float best = -1.f; int bn = 0;
        for (int n = 0; n < NOBJ; n++) {
            float tx1 = st[n][0], ty1 = st[n][1], tx2 = st[n][2], ty2 = st[n][3];
            float iw = fmaxf(fminf(tx2, px2) - fmaxf(tx1, px1), 0.f);
            float ih = fmaxf(fminf(ty2, py2) - fmaxf(ty1, py1), 0.f);
            float inter = iw * ih;
            float iou = inter / ((tx2 - tx1) * (ty2 - ty1) + pa - inter);
            if (iou > best) { best = iou; bn = n; }  // tie -> first n
        }
        float ov = best;
        for (int n = 0; n < NOBJ; n++)
            if (sbp[n] == p) { bn = n; ov = 2.0f; }  // last n wins
        int conf = slab[bn];
        if (ov < 0.5f) conf = -1;
        if (ov < 0.4f) conf = 0;
        conf_t[b * PP + p] = conf;
        if (conf > 0) {
            is_pos = 1;
            float mx1 = st[bn][0], my1 = st[bn][1], mx2 = st[bn][2], my2 = st[bn][3];
            float gcx = ((mx1 + mx2) * 0.5f - pr.x) / (0.1f * pr.z);
            float gcy = ((my1 + my2) * 0.5f - pr.y) / (0.1f * pr.w);
            float gw = logf((mx2 - mx1) / pr.z) / 0.2f;
            float gh = logf((my2 - my1) / pr.w) / 0.2f;
            float4 ld = ((const float4*)loc_data)[b * PP + p];
            s_l1 = smooth_l1(ld.x - gcx) + smooth_l1(ld.y - gcy) +
                   smooth_l1(ld.z - gw) + smooth_l1(ld.w - gh);
        }
    }
    __shared__ float rs[256]; __shared__ int rc[256];
    rs[tid] = s_l1; rc[tid] = is_pos; __syncthreads();
    for (int s = 128; s > 0; s >>= 1) {
        if (tid < s) { rs[tid] += rs[tid + s]; rc[tid] += rc[tid + s]; }
        __syncthreads();
    }
    if (tid == 0) {
        if (rs[0] != 0.f) atomicAdd(&cnt_f[1], rs[0]);
        if (rc[0])        atomicAdd(&cnt_i[0], rc[0]);
    }
}

// Proven 159us structure: 64 rows per one-shot block staged via coalesced
// float4 -> LDS; 4 threads/row serial scan with native exp2/log2.
// 7218 blocks * 5184 floats == ROWS*81 exactly.
__global__ void __launch_bounds__(256) k_conf(const float* __restrict__ conf_data,
                                              const int* __restrict__ conf_t,
                                              unsigned* __restrict__ key,
                                              float* __restrict__ ce,
                                              float* __restrict__ cnt_f) {
    __shared__ float sx[RPB * CC];   // 20736 B
    int tid = threadIdx.x;
    const float4* g = (const float4*)(conf_data + (size_t)blockIdx.x * (RPB * CC));
    float4* s4 = (float4*)sx;
    #pragma unroll
    for (int i = 0; i < 5; i++) s4[tid + 256 * i] = g[tid + 256 * i];
    if (tid < (RPB * CC / 4) - 1280) s4[1280 + tid] = g[1280 + tid];
    __syncthreads();

    int r = tid >> 2, t = tid & 3;
    int row = blockIdx.x * RPB + r;
    const float* x = sx + r * CC;

    float m = (t == 0) ? x[0] : -INFINITY;
    float fg = -INFINITY;
    for (int c = (t == 0) ? 4 : t; c < CC; c += 4) {
        float v = x[c];
        m = fmaxf(m, v);
        fg = fmaxf(fg, v);
    }
    m = fmaxf(m, __shfl_xor(m, 1));
    m = fmaxf(m, __shfl_xor(m, 2));
    fg = fmaxf(fg, __shfl_xor(fg, 1));
    fg = fmaxf(fg, __shfl_xor(fg, 2));

    const float LOG2E = 1.4426950408889634f;
    float e = 0.f;
    for (int c = t; c < CC; c += 4) e += exp2f((x[c] - m) * LOG2E);
    e += __shfl_xor(e, 1);
    e += __shfl_xor(e, 2);

    if (t == 0) {
        float lse = m + log2f(e) * 0.6931471805599453f;
        int ct = conf_t[row];
        int ctc = min(max(ct, 0), CC - 1);
        float cev = lse - x[ctc];
        ce[row] = cev;
        key[row] = (ct == 0) ? keymap(fg) : 0u;
        if (ct > 0) atomicAdd(&cnt_f[2], cev);
    }
}

// Level A: 2048-bin LDS histogram of key>>21 (negative candidates = key!=0),
// flushed to 8 spread global copies.
__global__ void __launch_bounds__(256) k_histA(const unsigned* __restrict__ key,
                                               unsigned* __restrict__ hA) {
    __shared__ unsigned lh[2048];
    int tid = threadIdx.x;
    for (int j = tid; j < 2048; j += 256) lh[j] = 0;
    __syncthreads();
    const uint4* k4 = (const uint4*)key;
    int n4 = ROWS / 4;
    for (int r = blockIdx.x * 256 + tid; r < n4; r += gridDim.x * 256) {
        uint4 k = k4[r];
        if (k.x) atomicAdd(&lh[k.x >> 21], 1u);
        if (k.y) atomicAdd(&lh[k.y >> 21], 1u);
        if (k.z) atomicAdd(&lh[k.z >> 21], 1u);
        if (k.w) atomicAdd(&lh[k.w >> 21], 1u);
    }
    __syncthreads();
    unsigned* hmy = hA + (blockIdx.x & 7) * 2048;
    for (int j = tid; j < 2048; j += 256)
        if (lh[j]) atomicAdd(&hmy[j], lh[j]);
}

// Level B: every block recomputes the level-A scan (deterministic), then
// histograms bits 20:10 of keys within prefixA.
__global__ void __launch_bounds__(256) k_histB(const unsigned* __restrict__ key,
                                               const int* __restrict__ cnt_i,
                                               const unsigned* __restrict__ hA,
                                               unsigned* __restrict__ hB) {
    unsigned Kr = 3u * (unsigned)cnt_i[0];
    if (Kr == 0) return;                     // negsum handles: select none
    unsigned remB;
    int binA = scan_bins<2048>(hA, Kr, &remB);
    if (binA < 0) return;                    // negsum handles: select all
    unsigned prefixA = (unsigned)binA;

    __shared__ unsigned lh[2048];
    int tid = threadIdx.x;
    for (int j = tid; j < 2048; j += 256) lh[j] = 0;
    __syncthreads();
    const uint4* k4 = (const uint4*)key;
    int n4 = ROWS / 4;
    for (int r = blockIdx.x * 256 + tid; r < n4; r += gridDim.x * 256) {
        uint4 k = k4[r];
        if ((k.x >> 21) == prefixA) atomicAdd(&lh[(k.x >> 10) & 0x7FFu], 1u);
        if ((k.y >> 21) == prefixA) atomicAdd(&lh[(k.y >> 10) & 0x7FFu], 1u);
        if ((k.z >> 21) == prefixA) atomicAdd(&lh[(k.z >> 10) & 0x7FFu], 1u);
        if ((k.w >> 21) == prefixA) atomicAdd(&lh[(k.w >> 10) & 0x7FFu], 1u);
    }
    __syncthreads();
    unsigned* hmy = hB + (blockIdx.x & 7) * 2048;
    for (int j = tid; j < 2048; j += 256)
        if (lh[j]) atomicAdd(&hmy[j], lh[j]);
}

// Level C: recompute scans A and B, then histogram bits 9:0 within prefixAB.
__global__ void __launch_bounds__(256) k_histC(const unsigned* __restrict__ key,
                                               const int* __restrict__ cnt_i,
                                               const unsigned* __restrict__ hA,
                                               const unsigned* __restrict__ hB,
                                               unsigned* __restrict__ hC) {
    unsigned Kr = 3u * (unsigned)cnt_i[0];
    if (Kr == 0) return;
    unsigned remB;
    int binA = scan_bins<2048>(hA, Kr, &remB);
    if (binA < 0) return;
    unsigned remC;
    int binB = scan_bins<2048>(hB, remB, &remC);
    if (binB < 0) { binB = 0; remC = 0; }    // defensive (cannot happen)
    unsigned prefixAB = ((unsigned)binA << 11) | (unsigned)binB;

    __shared__ unsigned lh[1024];
    int tid = threadIdx.x;
    for (int j = tid; j < 1024; j += 256) lh[j] = 0;
    __syncthreads();
    const uint4* k4 = (const uint4*)key;
    int n4 = ROWS / 4;
    for (int r = blockIdx.x * 256 + tid; r < n4; r += gridDim.x * 256) {
        uint4 k = k4[r];
        if ((k.x >> 10) == prefixAB) atomicAdd(&lh[k.x & 0x3FFu], 1u);
        if ((k.y >> 10) == prefixAB) atomicAdd(&lh[k.y & 0x3FFu], 1u);
        if ((k.z >> 10) == prefixAB) atomicAdd(&lh[k.z & 0x3FFu], 1u);
        if ((k.w >> 10) == prefixAB) atomicAdd(&lh[k.w & 0x3FFu], 1u);
    }
    __syncthreads();
    unsigned* hmy = hC + (blockIdx.x & 7) * 1024;
    for (int j = tid; j < 1024; j += 256)
        if (lh[j]) atomicAdd(&hmy[j], lh[j]);
}

// Recompute all three scans -> exact 32-bit threshold T + eqSlots, sum CE over
// selected negatives (candidates = key != 0; keymap of a finite float is never
// 0), and fold the final loss computation via the relaxed done-counter +
// vmcnt(0) publish pattern (r6/r7-proven, no cache-maintenance ops).
__global__ void __launch_bounds__(256) k_negsum(const unsigned* __restrict__ key,
                                                const float* __restrict__ ce,
                                                int* __restrict__ cnt_i,
                                                float* __restrict__ cnt_f,
                                                const unsigned* __restrict__ hA,
                                                const unsigned* __restrict__ hB,
                                                const unsigned* __restrict__ hC,
                                                float* __restrict__ out) {
    int tid = threadIdx.x;
    unsigned Kr = 3u * (unsigned)cnt_i[0];
    unsigned T; int eqS;
    if (Kr == 0) { T = 0xFFFFFFFFu; eqS = 0; }   // no positives: select none
    else {
        unsigned remB;
        int binA = scan_bins<2048>(hA, Kr, &remB);
        if (binA < 0) { T = 0u; eqS = 0; }       // total < Kr: select all
        else {
            unsigned remC;
            int binB = scan_bins<2048>(hB, remB, &remC);
            if (binB < 0) { binB = 0; remC = 0; }
            unsigned remD;
            int binC = scan_bins<1024>(hC, remC, &remD);
            if (binC < 0) { binC = 0; remD = 0; }
            T = ((unsigned)binA << 21) | ((unsigned)binB << 10) | (unsigned)binC;
            eqS = (int)remD;
        }
    }

    float s = 0.f; int c = 0;
    const uint4* k4 = (const uint4*)key;
    int n4 = ROWS / 4;
    for (int r = blockIdx.x * 256 + tid; r < n4; r += gridDim.x * 256) {
        uint4 k = k4[r];
        #define DO_ONE(comp, idx) { \
            unsigned kk = k.comp; \
            if (kk) { \
                bool selr = false; \
                if (kk > T) selr = true; \
                else if (kk == T) { int slot = atomicAdd(&cnt_i[5], 1); selr = slot < eqS; } \
                if (selr) { s += ce[4 * r + idx]; c++; } \
            } }
        DO_ONE(x, 0) DO_ONE(y, 1) DO_ONE(z, 2) DO_ONE(w, 3)
        #undef DO_ONE
    }
    __shared__ float rs[256]; __shared__ int rc[256];
    rs[tid] = s; rc[tid] = c; __syncthreads();
    for (int st = 128; st > 0; st >>= 1) {
        if (tid < st) { rs[tid] += rs[tid + st]; rc[tid] += rc[tid + st]; }
        __syncthreads();
    }
    if (tid == 0) {
        if (rs[0] != 0.f) atomicAdd(&cnt_f[3], rs[0]);
        if (rc[0])        atomicAdd(&cnt_i[4], rc[0]);
    }
    VMEM_DRAIN();   // my partial sums are at the coherence point
    if (tid == 0 &&
        __hip_atomic_fetch_add((unsigned*)&cnt_i[13], 1u,
            __ATOMIC_RELAXED, SCOPE_AGENT) == (unsigned)(gridDim.x - 1)) {
        int np = aload_i(&cnt_i[0]);
        int nn = aload_i(&cnt_i[4]);
        float f1 = aload_f(&cnt_f[1]);
        float f2 = aload_f(&cnt_f[2]);
        float f3 = aload_f(&cnt_f[3]);
        out[0] = f1 / (float)max(np, 1);
        out[1] = (f2 + f3) / (float)max(np + nn, 1);
    }
}

extern "C" void kernel_launch(void* const* d_in, const int* in_sizes, int n_in,
                              void* d_out, int out_size, void* d_ws, size_t ws_size,
                              hipStream_t stream) {
    const float* loc    = (const float*)d_in[0];
    const float* conf   = (const float*)d_in[1];
    const float* priors = (const float*)d_in[2];
    const float* gt     = (const float*)d_in[3];
    const int*   labels = (const int*)d_in[4];
    float* out = (float*)d_out;
    int*      wi = (int*)d_ws;
    float*    wf = (float*)d_ws;
    unsigned* wu = (unsigned*)d_ws;
    unsigned long long* wbp = (unsigned long long*)(wi + W_BP);

    hipMemsetAsync(d_ws, 0, MEMSET_BYTES, stream);  // counters + hists + bp
    k_best_prior<<<dim3(NOBJ, BB, BPSPLIT), 256, 0, stream>>>(priors, gt, wbp);
    k_match<<<dim3((PP + 255) / 256, BB), 256, 0, stream>>>(
        loc, priors, gt, labels, wbp, wi + W_CONF, wf, wi);
    k_conf<<<ROWS / RPB, 256, 0, stream>>>(conf, wi + W_CONF, wu + W_KEY,
                                           wf + W_CE, wf);
    k_histA<<<HISTBLK, 256, 0, stream>>>(wu + W_KEY, wu + W_HA);
    k_histB<<<HISTBLK, 256, 0, stream>>>(wu + W_KEY, wi, wu + W_HA, wu + W_HB);
    k_histC<<<HISTBLK, 256, 0, stream>>>(wu + W_KEY, wi, wu + W_HA, wu + W_HB,
                                         wu + W_HC);
    k_negsum<<<NEGBLK, 256, 0, stream>>>(wu + W_KEY, wf + W_CE, wi, wf,
                                         wu + W_HA, wu + W_HB, wu + W_HC, out);
}

// Round 10
// 428.504 us; speedup vs baseline: 1.1416x; 1.1416x over previous
//
#include <hip/hip_runtime.h>
#include <math.h>

#define BB 8
#define PP 57744
#define NOBJ 20
#define CC 81
#define ROWS (BB*PP)
#define RPB 128       // rows per block in k_conf (512 threads; same per-thread shape as proven 64/256)
#define CONFBLK (ROWS / RPB)   // 3609
#define BPSPLIT 16
#define BPCHUNK ((PP + BPSPLIT - 1) / BPSPLIT)   // 3609
#define HISTBLK 512
#define NEGBLK 512

// ws layout in 4-byte units
// cnt: [0]=num_pos [1]=sl1_sum(f) [2]=pos_ce(f) [3]=neg_ce(f) [4]=neg_cnt
//      [5]=eqCtr [13]=negsum_done
#define W_CNT  0                        // 64 words
#define W_HA   64                       // 8 copies x 2048 bins (bits 31:21)
#define W_HB   (W_HA + 8*2048)          // 8 copies x 2048 (bits 20:10)
#define W_HC   (W_HB + 8*2048)          // 8 copies x 1024 (bits 9:0)
#define W_BP   (W_HC + 8*1024)          // word 41024 (byte 164096, 8-aligned)
#define W_CONF (W_BP + 320)             // ROWS ints
#define W_KEY  (W_CONF + ROWS)          // ROWS uints
#define W_CE   (W_KEY + ROWS)           // ROWS floats
#define MEMSET_BYTES (W_CONF * 4)       // counters + hists + bp

#define SCOPE_AGENT __HIP_MEMORY_SCOPE_AGENT
// Completion ordering only (no buffer_wbl2/buffer_inv cache maintenance —
// the round-5 410us lesson): prior vmem ops retired at the coherence point.
#define VMEM_DRAIN() asm volatile("s_waitcnt vmcnt(0) lgkmcnt(0)" ::: "memory")

__device__ __forceinline__ unsigned keymap(float f) {
    unsigned u = __float_as_uint(f);
    return (u & 0x80000000u) ? ~u : (u | 0x80000000u);
}

__device__ __forceinline__ float smooth_l1(float d) {
    float a = fabsf(d);
    return a < 1.f ? 0.5f * d * d : a - 0.5f;
}

__device__ __forceinline__ int aload_i(const int* p) {
    return __hip_atomic_load(p, __ATOMIC_RELAXED, SCOPE_AGENT);
}
__device__ __forceinline__ float aload_f(const float* p) {
    return __hip_atomic_load(p, __ATOMIC_RELAXED, SCOPE_AGENT);
}

// Descending-cumulative threshold search over NB bins summed across 8 global
// copies. PLAIN CACHED loads: the hist copies are always written by a PRIOR
// kernel, and dispatch boundaries give device-scope acquire/release (same
// guarantee k_conf relies on to read conf_t) — the r9 agent-scope atomic
// loads were unnecessary uncached traffic and cost ~30us. Deterministic, so
// every block recomputes it redundantly (no grid sync needed).
template <int NB>
__device__ int scan_bins(const unsigned* __restrict__ h, unsigned Kr,
                         unsigned* rem_out) {
    constexpr int BPT = NB / 256;
    __shared__ unsigned stot[256];
    __shared__ int sbin;
    __shared__ unsigned srem;
    __syncthreads();                 // protect shared reuse across calls
    int i = threadIdx.x & 255;       // scan uses first 256 threads' lanes only
    unsigned v[BPT];
    unsigned tot = 0;
    #pragma unroll
    for (int j = 0; j < BPT; j++) {
        unsigned s = 0;
        #pragma unroll
        for (int c = 0; c < 8; c++) s += h[c * NB + i * BPT + j];
        v[j] = s; tot += s;
    }
    if (threadIdx.x == 0) sbin = -1;
    if (threadIdx.x < 256) stot[i] = tot;
    __syncthreads();
    if (threadIdx.x < 256) {
        for (int off = 1; off < 256; off <<= 1) {   // inclusive suffix scan
            unsigned add = (i + off < 256) ? stot[i + off] : 0u;
            __syncthreads(); stot[i] += add; __syncthreads();
        }
        unsigned cum = (i < 255) ? stot[i + 1] : 0u;   // suffix of threads > i
        #pragma unroll
        for (int j = BPT - 1; j >= 0; j--) {
            unsigned nxt = cum;      // suffix(bin+1)
            cum += v[j];             // suffix(bin)
            if (cum >= Kr && nxt < Kr) { sbin = i * BPT + j; srem = Kr - nxt; }
        }
    } else {
        for (int off = 1; off < 256; off <<= 1) { __syncthreads(); __syncthreads(); }
    }
    __syncthreads();
    *rem_out = (sbin >= 0) ? srem : 0u;
    return sbin;
}

// Grid (NOBJ, BB, BPSPLIT): per-(gt,batch) argmax over a prior chunk, packed
// (iou_bits<<32)|(~p) so u64 max == (max iou, lowest prior idx).
__global__ void k_best_prior(const float* __restrict__ priors,
                             const float* __restrict__ gt,
                             unsigned long long* __restrict__ bp) {
    int n = blockIdx.x, b = blockIdx.y;
    int p0 = blockIdx.z * BPCHUNK;
    int p1 = min(p0 + BPCHUNK, PP);
    const float* t = gt + (b * NOBJ + n) * 4;
    float tx1 = t[0], ty1 = t[1], tx2 = t[2], ty2 = t[3];
    float ta = (tx2 - tx1) * (ty2 - ty1);
    unsigned long long best = 0ull;
    for (int p = p0 + threadIdx.x; p < p1; p += 256) {
        float4 pr = ((const float4*)priors)[p];
        float px1 = pr.x - pr.z * 0.5f, py1 = pr.y - pr.w * 0.5f;
        float px2 = pr.x + pr.z * 0.5f, py2 = pr.y + pr.w * 0.5f;
        float iw = fmaxf(fminf(tx2, px2) - fmaxf(tx1, px1), 0.f);
        float ih = fmaxf(fminf(ty2, py2) - fmaxf(ty1, py1), 0.f);
        float inter = iw * ih;
        float iou = inter / (ta + (px2 - px1) * (py2 - py1) - inter);
        unsigned long long pk = ((unsigned long long)__float_as_uint(iou) << 32)
                              | (unsigned long long)(0xFFFFFFFFu - (unsigned)p);
        if (pk > best) best = pk;
    }
    __shared__ unsigned long long sb[256];
    int tid = threadIdx.x;
    sb[tid] = best; __syncthreads();
    for (int s = 128; s > 0; s >>= 1) {
        if (tid < s && sb[tid + s] > sb[tid]) sb[tid] = sb[tid + s];
        __syncthreads();
    }
    if (tid == 0) atomicMax(&bp[b * NOBJ + n], sb[0]);
}

// Per prior: best truth (argmax over 20, tie->first), force-match (last gt wins),
// conf_t, and smooth-L1 loc loss for positives.
__global__ void k_match(const float* __restrict__ loc_data,
                        const float* __restrict__ priors,
                        const float* __restrict__ gt,
                        const int* __restrict__ labels,
                        const unsigned long long* __restrict__ bp,
                        int* __restrict__ conf_t,
                        float* __restrict__ cnt_f,
                        int* __restrict__ cnt_i) {
    int b = blockIdx.y;
    int tid = threadIdx.x;
    int p = blockIdx.x * 256 + tid;
    __shared__ float st[NOBJ][4];
    __shared__ int slab[NOBJ], sbp[NOBJ];
    if (tid < NOBJ * 4) ((float*)st)[tid] = gt[b * NOBJ * 4 + tid];
    if (tid < NOBJ) {
        slab[tid] = labels[b * NOBJ + tid];
        sbp[tid] = (int)(0xFFFFFFFFu - (unsigned)bp[b * NOBJ + tid]);
    }
    __syncthreads();
    float s_l1 = 0.f; int is_pos = 0;
    if (p < PP) {
        float4 pr = ((const float4*)priors)[p];
        float px1 = pr.x - pr.z * 0.5f, py1 = pr.y - pr.w * 0.5f;
        float px2 = pr.x + pr.z * 0.5f, py2 = pr.y + pr.w * 0.5f;
        float pa = (px2 - px1) * (py2 - py1);
        float best = -1.f; int bn = 0;
        for (int n = 0; n < NOBJ; n++) {
            float tx1 = st[n][0], ty1 = st[n][1], tx2 = st[n][2], ty2 = st[n][3];
            float iw = fmaxf(fminf(tx2, px2) - fmaxf(tx1, px1), 0.f);
            float ih = fmaxf(fminf(ty2, py2) - fmaxf(ty1, py1), 0.f);
            float inter = iw * ih;
            float iou = inter / ((tx2 - tx1) * (ty2 - ty1) + pa - inter);
            if (iou > best) { best = iou; bn = n; }  // tie -> first n
        }
        float ov = best;
        for (int n = 0; n < NOBJ; n++)
            if (sbp[n] == p) { bn = n; ov = 2.0f; }  // last n wins
        int conf = slab[bn];
        if (ov < 0.5f) conf = -1;
        if (ov < 0.4f) conf = 0;
        conf_t[b * PP + p] = conf;
        if (conf > 0) {
            is_pos = 1;
            float mx1 = st[bn][0], my1 = st[bn][1], mx2 = st[bn][2], my2 = st[bn][3];
            float gcx = ((mx1 + mx2) * 0.5f - pr.x) / (0.1f * pr.z);
            float gcy = ((my1 + my2) * 0.5f - pr.y) / (0.1f * pr.w);
            float gw = logf((mx2 - mx1) / pr.z) / 0.2f;
            float gh = logf((my2 - my1) / pr.w) / 0.2f;
            float4 ld = ((const float4*)loc_data)[b * PP + p];
            s_l1 = smooth_l1(ld.x - gcx) + smooth_l1(ld.y - gcy) +
                   smooth_l1(ld.z - gw) + smooth_l1(ld.w - gh);
        }
    }
    __shared__ float rs[256]; __shared__ int rc[256];
    rs[tid] = s_l1; rc[tid] = is_pos; __syncthreads();
    for (int s = 128; s > 0; s >>= 1) {
        if (tid < s) { rs[tid] += rs[tid + s]; rc[tid] += rc[tid + s]; }
        __syncthreads();
    }
    if (tid == 0) {
        if (rs[0] != 0.f) atomicAdd(&cnt_f[1], rs[0]);
        if (rc[0])        atomicAdd(&cnt_i[0], rc[0]);
    }
}

// Proven structure scaled 2x: 128 rows per one-shot block (512 threads)
// staged via coalesced float4 -> LDS; 4 threads/row serial scan with native
// exp2/log2. Per-thread shape identical to the 159us RPB=64 kernel (5 float4
// stage + 1 row per 4-lane group); only the grid halves to 3609 blocks —
// direct test of the 42-45 blocks/us dispatch-rate hypothesis from r8's
// linear split timing. LDS 41.5KB -> 3 blocks/CU = 24 waves/CU.
__global__ void __launch_bounds__(512) k_conf(const float* __restrict__ conf_data,
                                              const int* __restrict__ conf_t,
                                              unsigned* __restrict__ key,
                                              float* __restrict__ ce,
                                              float* __restrict__ cnt_f) {
    __shared__ float sx[RPB * CC];   // 41472 B
    int tid = threadIdx.x;
    const float4* g = (const float4*)(conf_data + (size_t)blockIdx.x * (RPB * CC));
    float4* s4 = (float4*)sx;
    #pragma unroll
    for (int i = 0; i < 5; i++) s4[tid + 512 * i] = g[tid + 512 * i];
    if (tid < (RPB * CC / 4) - 2560) s4[2560 + tid] = g[2560 + tid];
    __syncthreads();

    int r = tid >> 2, t = tid & 3;
    int row = blockIdx.x * RPB + r;
    const float* x = sx + r * CC;

    float m = (t == 0) ? x[0] : -INFINITY;
    float fg = -INFINITY;
    for (int c = (t == 0) ? 4 : t; c < CC; c += 4) {
        float v = x[c];
        m = fmaxf(m, v);
        fg = fmaxf(fg, v);
    }
    m = fmaxf(m, __shfl_xor(m, 1));
    m = fmaxf(m, __shfl_xor(m, 2));
    fg = fmaxf(fg, __shfl_xor(fg, 1));
    fg = fmaxf(fg, __shfl_xor(fg, 2));

    const float LOG2E = 1.4426950408889634f;
    float e = 0.f;
    for (int c = t; c < CC; c += 4) e += exp2f((x[c] - m) * LOG2E);
    e += __shfl_xor(e, 1);
    e += __shfl_xor(e, 2);

    if (t == 0) {
        float lse = m + log2f(e) * 0.6931471805599453f;
        int ct = conf_t[row];
        int ctc = min(max(ct, 0), CC - 1);
        float cev = lse - x[ctc];
        ce[row] = cev;
        key[row] = (ct == 0) ? keymap(fg) : 0u;
        if (ct > 0) atomicAdd(&cnt_f[2], cev);
    }
}

// Level A: 2048-bin LDS histogram of key>>21 (negative candidates = key!=0),
// flushed to 8 spread global copies.
__global__ void __launch_bounds__(256) k_histA(const unsigned* __restrict__ key,
                                               unsigned* __restrict__ hA) {
    __shared__ unsigned lh[2048];
    int tid = threadIdx.x;
    for (int j = tid; j < 2048; j += 256) lh[j] = 0;
    __syncthreads();
    const uint4* k4 = (const uint4*)key;
    int n4 = ROWS / 4;
    for (int r = blockIdx.x * 256 + tid; r < n4; r += gridDim.x * 256) {
        uint4 k = k4[r];
        if (k.x) atomicAdd(&lh[k.x >> 21], 1u);
        if (k.y) atomicAdd(&lh[k.y >> 21], 1u);
        if (k.z) atomicAdd(&lh[k.z >> 21], 1u);
        if (k.w) atomicAdd(&lh[k.w >> 21], 1u);
    }
    __syncthreads();
    unsigned* hmy = hA + (blockIdx.x & 7) * 2048;
    for (int j = tid; j < 2048; j += 256)
        if (lh[j]) atomicAdd(&hmy[j], lh[j]);
}

// Level B: every block recomputes the level-A scan (deterministic, cached
// loads), then histograms bits 20:10 of keys within prefixA.
__global__ void __launch_bounds__(256) k_histB(const unsigned* __restrict__ key,
                                               const int* __restrict__ cnt_i,
                                               const unsigned* __restrict__ hA,
                                               unsigned* __restrict__ hB) {
    unsigned Kr = 3u * (unsigned)cnt_i[0];
    if (Kr == 0) return;                     // negsum handles: select none
    unsigned remB;
    int binA = scan_bins<2048>(hA, Kr, &remB);
    if (binA < 0) return;                    // negsum handles: select all
    unsigned prefixA = (unsigned)binA;

    __shared__ unsigned lh[2048];
    int tid = threadIdx.x;
    for (int j = tid; j < 2048; j += 256) lh[j] = 0;
    __syncthreads();
    const uint4* k4 = (const uint4*)key;
    int n4 = ROWS / 4;
    for (int r = blockIdx.x * 256 + tid; r < n4; r += gridDim.x * 256) {
        uint4 k = k4[r];
        if ((k.x >> 21) == prefixA) atomicAdd(&lh[(k.x >> 10) & 0x7FFu], 1u);
        if ((k.y >> 21) == prefixA) atomicAdd(&lh[(k.y >> 10) & 0x7FFu], 1u);
        if ((k.z >> 21) == prefixA) atomicAdd(&lh[(k.z >> 10) & 0x7FFu], 1u);
        if ((k.w >> 21) == prefixA) atomicAdd(&lh[(k.w >> 10) & 0x7FFu], 1u);
    }
    __syncthreads();
    unsigned* hmy = hB + (blockIdx.x & 7) * 2048;
    for (int j = tid; j < 2048; j += 256)
        if (lh[j]) atomicAdd(&hmy[j], lh[j]);
}

// Level C: recompute scans A and B, then histogram bits 9:0 within prefixAB.
__global__ void __launch_bounds__(256) k_histC(const unsigned* __restrict__ key,
                                               const int* __restrict__ cnt_i,
                                               const unsigned* __restrict__ hA,
                                               const unsigned* __restrict__ hB,
                                               unsigned* __restrict__ hC) {
    unsigned Kr = 3u * (unsigned)cnt_i[0];
    if (Kr == 0) return;
    unsigned remB;
    int binA = scan_bins<2048>(hA, Kr, &remB);
    if (binA < 0) return;
    unsigned remC;
    int binB = scan_bins<2048>(hB, remB, &remC);
    if (binB < 0) { binB = 0; remC = 0; }    // defensive (cannot happen)
    unsigned prefixAB = ((unsigned)binA << 11) | (unsigned)binB;

    __shared__ unsigned lh[1024];
    int tid = threadIdx.x;
    for (int j = tid; j < 1024; j += 256) lh[j] = 0;
    __syncthreads();
    const uint4* k4 = (const uint4*)key;
    int n4 = ROWS / 4;
    for (int r = blockIdx.x * 256 + tid; r < n4; r += gridDim.x * 256) {
        uint4 k = k4[r];
        if ((k.x >> 10) == prefixAB) atomicAdd(&lh[k.x & 0x3FFu], 1u);
        if ((k.y >> 10) == prefixAB) atomicAdd(&lh[k.y & 0x3FFu], 1u);
        if ((k.z >> 10) == prefixAB) atomicAdd(&lh[k.z & 0x3FFu], 1u);
        if ((k.w >> 10) == prefixAB) atomicAdd(&lh[k.w & 0x3FFu], 1u);
    }
    __syncthreads();
    unsigned* hmy = hC + (blockIdx.x & 7) * 1024;
    for (int j = tid; j < 1024; j += 256)
        if (lh[j]) atomicAdd(&hmy[j], lh[j]);
}

// Recompute all three scans (cached loads) -> exact 32-bit threshold T +
// eqSlots, sum CE over selected negatives (candidates = key != 0), and fold
// the final loss computation via the relaxed done-counter + vmcnt(0) publish
// pattern (r6/r7-proven; only place needing same-kernel cross-block data).
__global__ void __launch_bounds__(256) k_negsum(const unsigned* __restrict__ key,
                                                const float* __restrict__ ce,
                                                int* __restrict__ cnt_i,
                                                float* __restrict__ cnt_f,
                                                const unsigned* __restrict__ hA,
                                                const unsigned* __restrict__ hB,
                                                const unsigned* __restrict__ hC,
                                                float* __restrict__ out) {
    int tid = threadIdx.x;
    unsigned Kr = 3u * (unsigned)cnt_i[0];
    unsigned T; int eqS;
    if (Kr == 0) { T = 0xFFFFFFFFu; eqS = 0; }   // no positives: select none
    else {
        unsigned remB;
        int binA = scan_bins<2048>(hA, Kr, &remB);
        if (binA < 0) { T = 0u; eqS = 0; }       // total < Kr: select all
        else {
            unsigned remC;
            int binB = scan_bins<2048>(hB, remB, &remC);
            if (binB < 0) { binB = 0; remC = 0; }
            unsigned remD;
            int binC = scan_bins<1024>(hC, remC, &remD);
            if (binC < 0) { binC = 0; remD = 0; }
            T = ((unsigned)binA << 21) | ((unsigned)binB << 10) | (unsigned)binC;
            eqS = (int)remD;
        }
    }

    float s = 0.f; int c = 0;
    const uint4* k4 = (const uint4*)key;
    int n4 = ROWS / 4;
    for (int r = blockIdx.x * 256 + tid; r < n4; r += gridDim.x * 256) {
        uint4 k = k4[r];
        #define DO_ONE(comp, idx) { \
            unsigned kk = k.comp; \
            if (kk) { \
                bool selr = false; \
                if (kk > T) selr = true; \
                else if (kk == T) { int slot = atomicAdd(&cnt_i[5], 1); selr = slot < eqS; } \
                if (selr) { s += ce[4 * r + idx]; c++; } \
            } }
        DO_ONE(x, 0) DO_ONE(y, 1) DO_ONE(z, 2) DO_ONE(w, 3)
        #undef DO_ONE
    }
    __shared__ float rs[256]; __shared__ int rc[256];
    rs[tid] = s; rc[tid] = c; __syncthreads();
    for (int st = 128; st > 0; st >>= 1) {
        if (tid < st) { rs[tid] += rs[tid + st]; rc[tid] += rc[tid + st]; }
        __syncthreads();
    }
    if (tid == 0) {
        if (rs[0] != 0.f) atomicAdd(&cnt_f[3], rs[0]);
        if (rc[0])        atomicAdd(&cnt_i[4], rc[0]);
    }
    VMEM_DRAIN();   // my partial sums are at the coherence point
    if (tid == 0 &&
        __hip_atomic_fetch_add((unsigned*)&cnt_i[13], 1u,
            __ATOMIC_RELAXED, SCOPE_AGENT) == (unsigned)(gridDim.x - 1)) {
        int np = aload_i(&cnt_i[0]);
        int nn = aload_i(&cnt_i[4]);
        float f1 = aload_f(&cnt_f[1]);
        float f2 = aload_f(&cnt_f[2]);
        float f3 = aload_f(&cnt_f[3]);
        out[0] = f1 / (float)max(np, 1);
        out[1] = (f2 + f3) / (float)max(np + nn, 1);
    }
}

extern "C" void kernel_launch(void* const* d_in, const int* in_sizes, int n_in,
                              void* d_out, int out_size, void* d_ws, size_t ws_size,
                              hipStream_t stream) {
    const float* loc    = (const float*)d_in[0];
    const float* conf   = (const float*)d_in[1];
    const float* priors = (const float*)d_in[2];
    const float* gt     = (const float*)d_in[3];
    const int*   labels = (const int*)d_in[4];
    float* out = (float*)d_out;
    int*      wi = (int*)d_ws;
    float*    wf = (float*)d_ws;
    unsigned* wu = (unsigned*)d_ws;
    unsigned long long* wbp = (unsigned long long*)(wi + W_BP);

    hipMemsetAsync(d_ws, 0, MEMSET_BYTES, stream);  // counters + hists + bp
    k_best_prior<<<dim3(NOBJ, BB, BPSPLIT), 256, 0, stream>>>(priors, gt, wbp);
    k_match<<<dim3((PP + 255) / 256, BB), 256, 0, stream>>>(
        loc, priors, gt, labels, wbp, wi + W_CONF, wf, wi);
    k_conf<<<CONFBLK, 512, 0, stream>>>(conf, wi + W_CONF, wu + W_KEY,
                                        wf + W_CE, wf);
    k_histA<<<HISTBLK, 256, 0, stream>>>(wu + W_KEY, wu + W_HA);
    k_histB<<<HISTBLK, 256, 0, stream>>>(wu + W_KEY, wi, wu + W_HA, wu + W_HB);
    k_histC<<<HISTBLK, 256, 0, stream>>>(wu + W_KEY, wi, wu + W_HA, wu + W_HB,
                                         wu + W_HC);
    k_negsum<<<NEGBLK, 256, 0, stream>>>(wu + W_KEY, wf + W_CE, wi, wf,
                                         wu + W_HA, wu + W_HB, wu + W_HC, out);
}

// Round 11
// 372.093 us; speedup vs baseline: 1.3147x; 1.1516x over previous
//
#include <hip/hip_runtime.h>
#include <math.h>

#define BB 8
#define PP 57744
#define NOBJ 20
#define CC 81
#define ROWS (BB*PP)
#define RPB 64        // rows per block in k_conf: 64 threads, ONE ROW PER LANE
#define CONFBLK (ROWS / RPB)   // 7218
#define BPSPLIT 16
#define BPCHUNK ((PP + BPSPLIT - 1) / BPSPLIT)   // 3609
#define HISTBLK 512
#define NEGBLK 512

// ws layout in 4-byte units
// cnt: [0]=num_pos [1]=sl1_sum(f) [2]=pos_ce(f) [3]=neg_ce(f) [4]=neg_cnt
//      [5]=eqCtr [13]=negsum_done
#define W_CNT  0                        // 64 words
#define W_HA   64                       // 8 copies x 2048 bins (bits 31:21)
#define W_HB   (W_HA + 8*2048)          // 8 copies x 2048 (bits 20:10)
#define W_HC   (W_HB + 8*2048)          // 8 copies x 1024 (bits 9:0)
#define W_BP   (W_HC + 8*1024)          // word 41024 (byte 164096, 8-aligned)
#define W_CONF (W_BP + 320)             // ROWS ints
#define W_KEY  (W_CONF + ROWS)          // ROWS uints
#define W_CE   (W_KEY + ROWS)           // ROWS floats
#define MEMSET_BYTES (W_CONF * 4)       // counters + hists + bp

#define SCOPE_AGENT __HIP_MEMORY_SCOPE_AGENT
// Completion ordering only (no buffer_wbl2/buffer_inv cache maintenance —
// the round-5 410us lesson): prior vmem ops retired at the coherence point.
#define VMEM_DRAIN() asm volatile("s_waitcnt vmcnt(0) lgkmcnt(0)" ::: "memory")

__device__ __forceinline__ unsigned keymap(float f) {
    unsigned u = __float_as_uint(f);
    return (u & 0x80000000u) ? ~u : (u | 0x80000000u);
}

__device__ __forceinline__ float smooth_l1(float d) {
    float a = fabsf(d);
    return a < 1.f ? 0.5f * d * d : a - 0.5f;
}

__device__ __forceinline__ int aload_i(const int* p) {
    return __hip_atomic_load(p, __ATOMIC_RELAXED, SCOPE_AGENT);
}
__device__ __forceinline__ float aload_f(const float* p) {
    return __hip_atomic_load(p, __ATOMIC_RELAXED, SCOPE_AGENT);
}

// Descending-cumulative threshold search over NB bins summed across 8 global
// copies, plain cached loads (hist written by a PRIOR kernel; dispatch
// boundaries provide coherence). Deterministic -> every block recomputes it.
template <int NB>
__device__ int scan_bins(const unsigned* __restrict__ h, unsigned Kr,
                         unsigned* rem_out) {
    constexpr int BPT = NB / 256;
    __shared__ unsigned stot[256];
    __shared__ int sbin;
    __shared__ unsigned srem;
    __syncthreads();                 // protect shared reuse across calls
    int i = threadIdx.x & 255;
    unsigned v[BPT];
    unsigned tot = 0;
    #pragma unroll
    for (int j = 0; j < BPT; j++) {
        unsigned s = 0;
        #pragma unroll
        for (int c = 0; c < 8; c++) s += h[c * NB + i * BPT + j];
        v[j] = s; tot += s;
    }
    if (threadIdx.x == 0) sbin = -1;
    if (threadIdx.x < 256) stot[i] = tot;
    __syncthreads();
    if (threadIdx.x < 256) {
        for (int off = 1; off < 256; off <<= 1) {   // inclusive suffix scan
            unsigned add = (i + off < 256) ? stot[i + off] : 0u;
            __syncthreads(); stot[i] += add; __syncthreads();
        }
        unsigned cum = (i < 255) ? stot[i + 1] : 0u;
        #pragma unroll
        for (int j = BPT - 1; j >= 0; j--) {
            unsigned nxt = cum;      // suffix(bin+1)
            cum += v[j];             // suffix(bin)
            if (cum >= Kr && nxt < Kr) { sbin = i * BPT + j; srem = Kr - nxt; }
        }
    } else {
        for (int off = 1; off < 256; off <<= 1) { __syncthreads(); __syncthreads(); }
    }
    __syncthreads();
    *rem_out = (sbin >= 0) ? srem : 0u;
    return sbin;
}

// Grid (NOBJ, BB, BPSPLIT): per-(gt,batch) argmax over a prior chunk, packed
// (iou_bits<<32)|(~p) so u64 max == (max iou, lowest prior idx).
__global__ void k_best_prior(const float* __restrict__ priors,
                             const float* __restrict__ gt,
                             unsigned long long* __restrict__ bp) {
    int n = blockIdx.x, b = blockIdx.y;
    int p0 = blockIdx.z * BPCHUNK;
    int p1 = min(p0 + BPCHUNK, PP);
    const float* t = gt + (b * NOBJ + n) * 4;
    float tx1 = t[0], ty1 = t[1], tx2 = t[2], ty2 = t[3];
    float ta = (tx2 - tx1) * (ty2 - ty1);
    unsigned long long best = 0ull;
    for (int p = p0 + threadIdx.x; p < p1; p += 256) {
        float4 pr = ((const float4*)priors)[p];
        float px1 = pr.x - pr.z * 0.5f, py1 = pr.y - pr.w * 0.5f;
        float px2 = pr.x + pr.z * 0.5f, py2 = pr.y + pr.w * 0.5f;
        float iw = fmaxf(fminf(tx2, px2) - fmaxf(tx1, px1), 0.f);
        float ih = fmaxf(fminf(ty2, py2) - fmaxf(ty1, py1), 0.f);
        float inter = iw * ih;
        float iou = inter / (ta + (px2 - px1) * (py2 - py1) - inter);
        unsigned long long pk = ((unsigned long long)__float_as_uint(iou) << 32)
                              | (unsigned long long)(0xFFFFFFFFu - (unsigned)p);
        if (pk > best) best = pk;
    }
    __shared__ unsigned long long sb[256];
    int tid = threadIdx.x;
    sb[tid] = best; __syncthreads();
    for (int s = 128; s > 0; s >>= 1) {
        if (tid < s && sb[tid + s] > sb[tid]) sb[tid] = sb[tid + s];
        __syncthreads();
    }
    if (tid == 0) atomicMax(&bp[b * NOBJ + n], sb[0]);
}

// Per prior: best truth (argmax over 20, tie->first), force-match (last gt wins),
// conf_t, and smooth-L1 loc loss for positives.
__global__ void k_match(const float* __restrict__ loc_data,
                        const float* __restrict__ priors,
                        const float* __restrict__ gt,
                        const int* __restrict__ labels,
                        const unsigned long long* __restrict__ bp,
                        int* __restrict__ conf_t,
                        float* __restrict__ cnt_f,
                        int* __restrict__ cnt_i) {
    int b = blockIdx.y;
    int tid = threadIdx.x;
    int p = blockIdx.x * 256 + tid;
    __shared__ float st[NOBJ][4];
    __shared__ int slab[NOBJ], sbp[NOBJ];
    if (tid < NOBJ * 4) ((float*)st)[tid] = gt[b * NOBJ * 4 + tid];
    if (tid < NOBJ) {
        slab[tid] = labels[b * NOBJ + tid];
        sbp[tid] = (int)(0xFFFFFFFFu - (unsigned)bp[b * NOBJ + tid]);
    }
    __syncthreads();
    float s_l1 = 0.f; int is_pos = 0;
    if (p < PP) {
        float4 pr = ((const float4*)priors)[p];
        float px1 = pr.x - pr.z * 0.5f, py1 = pr.y - pr.w * 0.5f;
        float px2 = pr.x + pr.z * 0.5f, py2 = pr.y + pr.w * 0.5f;
        float pa = (px2 - px1) * (py2 - py1);
        float best = -1.f; int bn = 0;
        for (int n = 0; n < NOBJ; n++) {
            float tx1 = st[n][0], ty1 = st[n][1], tx2 = st[n][2], ty2 = st[n][3];
            float iw = fmaxf(fminf(tx2, px2) - fmaxf(tx1, px1), 0.f);
            float ih = fmaxf(fminf(ty2, py2) - fmaxf(ty1, py1), 0.f);
            float inter = iw * ih;
            float iou = inter / ((tx2 - tx1) * (ty2 - ty1) + pa - inter);
            if (iou > best) { best = iou; bn = n; }  // tie -> first n
        }
        float ov = best;
        for (int n = 0; n < NOBJ; n++)
            if (sbp[n] == p) { bn = n; ov = 2.0f; }  // last n wins
        int conf = slab[bn];
        if (ov < 0.5f) conf = -1;
        if (ov < 0.4f) conf = 0;
        conf_t[b * PP + p] = conf;
        if (conf > 0) {
            is_pos = 1;
            float mx1 = st[bn][0], my1 = st[bn][1], mx2 = st[bn][2], my2 = st[bn][3];
            float gcx = ((mx1 + mx2) * 0.5f - pr.x) / (0.1f * pr.z);
            float gcy = ((my1 + my2) * 0.5f - pr.y) / (0.1f * pr.w);
            float gw = logf((mx2 - mx1) / pr.z) / 0.2f;
            float gh = logf((my2 - my1) / pr.w) / 0.2f;
            float4 ld = ((const float4*)loc_data)[b * PP + p];
            s_l1 = smooth_l1(ld.x - gcx) + smooth_l1(ld.y - gcy) +
                   smooth_l1(ld.z - gw) + smooth_l1(ld.w - gh);
        }
    }
    __shared__ float rs[256]; __shared__ int rc[256];
    rs[tid] = s_l1; rc[tid] = is_pos; __syncthreads();
    for (int s = 128; s > 0; s >>= 1) {
        if (tid < s) { rs[tid] += rs[tid + s]; rc[tid] += rc[tid + s]; }
        __syncthreads();
    }
    if (tid == 0) {
        if (rs[0] != 0.f) atomicAdd(&cnt_f[1], rs[0]);
        if (rc[0])        atomicAdd(&cnt_i[0], rc[0]);
    }
}

// ROW-PER-LANE experiment: 64-thread (1-wave) blocks, 64 rows per block
// staged via coalesced float4 -> LDS (1296 float4 = 20.25/lane), then each
// LANE processes one full row in-lane: no shuffles, no t==0 divergence,
// coalesced conf_t/key/ce accesses. LDS reads at lane-stride 81 words
// (81 mod 32 = 17, odd -> exactly 2 lanes/bank = conflict-free). fmax/exp
// chains split 4-way for ILP. 7218 waves total (4x fewer than the 159us
// 4-lane/row variants) — discriminates the per-wave vs per-row cost law.
__global__ void __launch_bounds__(64) k_conf(const float* __restrict__ conf_data,
                                             const int* __restrict__ conf_t,
                                             unsigned* __restrict__ key,
                                             float* __restrict__ ce,
                                             float* __restrict__ cnt_f) {
    __shared__ float sx[RPB * CC];   // 20736 B
    int l = threadIdx.x;
    const float4* g = (const float4*)(conf_data + (size_t)blockIdx.x * (RPB * CC));
    float4* s4 = (float4*)sx;
    #pragma unroll
    for (int i = 0; i < 20; i++) s4[l + 64 * i] = g[l + 64 * i];
    if (l < 16) s4[1280 + l] = g[1280 + l];
    int row = blockIdx.x * RPB + l;
    int ct = conf_t[row];            // coalesced, overlaps staging
    __syncthreads();

    const float* x = sx + l * CC;
    float x0 = x[0];
    // fg = max over classes 1..80 (4 accumulators for ILP; 1+4k..4+4k, k<20)
    float f0 = x[1], f1 = x[2], f2 = x[3], f3 = x[4];
    #pragma unroll
    for (int k = 1; k < 20; k++) {
        f0 = fmaxf(f0, x[1 + 4 * k]);
        f1 = fmaxf(f1, x[2 + 4 * k]);
        f2 = fmaxf(f2, x[3 + 4 * k]);
        f3 = fmaxf(f3, x[4 + 4 * k]);
    }
    float fg = fmaxf(fmaxf(f0, f1), fmaxf(f2, f3));
    float m = fmaxf(fg, x0);

    const float LOG2E = 1.4426950408889634f;
    float e0 = 0.f, e1 = 0.f, e2 = 0.f, e3 = 0.f;
    #pragma unroll
    for (int k = 0; k < 20; k++) {
        e0 += exp2f((x[4 * k]     - m) * LOG2E);
        e1 += exp2f((x[4 * k + 1] - m) * LOG2E);
        e2 += exp2f((x[4 * k + 2] - m) * LOG2E);
        e3 += exp2f((x[4 * k + 3] - m) * LOG2E);
    }
    float e = (e0 + e1) + (e2 + e3) + exp2f((x[80] - m) * LOG2E);

    float lse = m + log2f(e) * 0.6931471805599453f;
    int ctc = min(max(ct, 0), CC - 1);
    float cev = lse - x[ctc];
    ce[row] = cev;                   // coalesced
    key[row] = (ct == 0) ? keymap(fg) : 0u;   // coalesced
    if (ct > 0) atomicAdd(&cnt_f[2], cev);
}

// Level A: 2048-bin LDS histogram of key>>21 (negative candidates = key!=0),
// flushed to 8 spread global copies.
__global__ void __launch_bounds__(256) k_histA(const unsigned* __restrict__ key,
                                               unsigned* __restrict__ hA) {
    __shared__ unsigned lh[2048];
    int tid = threadIdx.x;
    for (int j = tid; j < 2048; j += 256) lh[j] = 0;
    __syncthreads();
    const uint4* k4 = (const uint4*)key;
    int n4 = ROWS / 4;
    for (int r = blockIdx.x * 256 + tid; r < n4; r += gridDim.x * 256) {
        uint4 k = k4[r];
        if (k.x) atomicAdd(&lh[k.x >> 21], 1u);
        if (k.y) atomicAdd(&lh[k.y >> 21], 1u);
        if (k.z) atomicAdd(&lh[k.z >> 21], 1u);
        if (k.w) atomicAdd(&lh[k.w >> 21], 1u);
    }
    __syncthreads();
    unsigned* hmy = hA + (blockIdx.x & 7) * 2048;
    for (int j = tid; j < 2048; j += 256)
        if (lh[j]) atomicAdd(&hmy[j], lh[j]);
}

// Level B: every block recomputes the level-A scan (deterministic, cached
// loads), then histograms bits 20:10 of keys within prefixA.
__global__ void __launch_bounds__(256) k_histB(const unsigned* __restrict__ key,
                                               const int* __restrict__ cnt_i,
                                               const unsigned* __restrict__ hA,
                                               unsigned* __restrict__ hB) {
    unsigned Kr = 3u * (unsigned)cnt_i[0];
    if (Kr == 0) return;                     // negsum handles: select none
    unsigned remB;
    int binA = scan_bins<2048>(hA, Kr, &remB);
    if (binA < 0) return;                    // negsum handles: select all
    unsigned prefixA = (unsigned)binA;

    __shared__ unsigned lh[2048];
    int tid = threadIdx.x;
    for (int j = tid; j < 2048; j += 256) lh[j] = 0;
    __syncthreads();
    const uint4* k4 = (const uint4*)key;
    int n4 = ROWS / 4;
    for (int r = blockIdx.x * 256 + tid; r < n4; r += gridDim.x * 256) {
        uint4 k = k4[r];
        if ((k.x >> 21) == prefixA) atomicAdd(&lh[(k.x >> 10) & 0x7FFu], 1u);
        if ((k.y >> 21) == prefixA) atomicAdd(&lh[(k.y >> 10) & 0x7FFu], 1u);
        if ((k.z >> 21) == prefixA) atomicAdd(&lh[(k.z >> 10) & 0x7FFu], 1u);
        if ((k.w >> 21) == prefixA) atomicAdd(&lh[(k.w >> 10) & 0x7FFu], 1u);
    }
    __syncthreads();
    unsigned* hmy = hB + (blockIdx.x & 7) * 2048;
    for (int j = tid; j < 2048; j += 256)
        if (lh[j]) atomicAdd(&hmy[j], lh[j]);
}

// Level C: recompute scans A and B, then histogram bits 9:0 within prefixAB.
__global__ void __launch_bounds__(256) k_histC(const unsigned* __restrict__ key,
                                               const int* __restrict__ cnt_i,
                                               const unsigned* __restrict__ hA,
                                               const unsigned* __restrict__ hB,
                                               unsigned* __restrict__ hC) {
    unsigned Kr = 3u * (unsigned)cnt_i[0];
    if (Kr == 0) return;
    unsigned remB;
    int binA = scan_bins<2048>(hA, Kr, &remB);
    if (binA < 0) return;
    unsigned remC;
    int binB = scan_bins<2048>(hB, remB, &remC);
    if (binB < 0) { binB = 0; remC = 0; }    // defensive (cannot happen)
    unsigned prefixAB = ((unsigned)binA << 11) | (unsigned)binB;

    __shared__ unsigned lh[1024];
    int tid = threadIdx.x;
    for (int j = tid; j < 1024; j += 256) lh[j] = 0;
    __syncthreads();
    const uint4* k4 = (const uint4*)key;
    int n4 = ROWS / 4;
    for (int r = blockIdx.x * 256 + tid; r < n4; r += gridDim.x * 256) {
        uint4 k = k4[r];
        if ((k.x >> 10) == prefixAB) atomicAdd(&lh[k.x & 0x3FFu], 1u);
        if ((k.y >> 10) == prefixAB) atomicAdd(&lh[k.y & 0x3FFu], 1u);
        if ((k.z >> 10) == prefixAB) atomicAdd(&lh[k.z & 0x3FFu], 1u);
        if ((k.w >> 10) == prefixAB) atomicAdd(&lh[k.w & 0x3FFu], 1u);
    }
    __syncthreads();
    unsigned* hmy = hC + (blockIdx.x & 7) * 1024;
    for (int j = tid; j < 1024; j += 256)
        if (lh[j]) atomicAdd(&hmy[j], lh[j]);
}

// Recompute all three scans (cached loads) -> exact 32-bit threshold T +
// eqSlots, sum CE over selected negatives (candidates = key != 0), and fold
// the final loss computation via the relaxed done-counter + vmcnt(0) publish
// pattern (r6/r7-proven; only place needing same-kernel cross-block data).
__global__ void __launch_bounds__(256) k_negsum(const unsigned* __restrict__ key,
                                                const float* __restrict__ ce,
                                                int* __restrict__ cnt_i,
                                                float* __restrict__ cnt_f,
                                                const unsigned* __restrict__ hA,
                                                const unsigned* __restrict__ hB,
                                                const unsigned* __restrict__ hC,
                                                float* __restrict__ out) {
    int tid = threadIdx.x;
    unsigned Kr = 3u * (unsigned)cnt_i[0];
    unsigned T; int eqS;
    if (Kr == 0) { T = 0xFFFFFFFFu; eqS = 0; }   // no positives: select none
    else {
        unsigned remB;
        int binA = scan_bins<2048>(hA, Kr, &remB);
        if (binA < 0) { T = 0u; eqS = 0; }       // total < Kr: select all
        else {
            unsigned remC;
            int binB = scan_bins<2048>(hB, remB, &remC);
            if (binB < 0) { binB = 0; remC = 0; }
            unsigned remD;
            int binC = scan_bins<1024>(hC, remC, &remD);
            if (binC < 0) { binC = 0; remD = 0; }
            T = ((unsigned)binA << 21) | ((unsigned)binB << 10) | (unsigned)binC;
            eqS = (int)remD;
        }
    }

    float s = 0.f; int c = 0;
    const uint4* k4 = (const uint4*)key;
    int n4 = ROWS / 4;
    for (int r = blockIdx.x * 256 + tid; r < n4; r += gridDim.x * 256) {
        uint4 k = k4[r];
        #define DO_ONE(comp, idx) { \
            unsigned kk = k.comp; \
            if (kk) { \
                bool selr = false; \
                if (kk > T) selr = true; \
                else if (kk == T) { int slot = atomicAdd(&cnt_i[5], 1); selr = slot < eqS; } \
                if (selr) { s += ce[4 * r + idx]; c++; } \
            } }
        DO_ONE(x, 0) DO_ONE(y, 1) DO_ONE(z, 2) DO_ONE(w, 3)
        #undef DO_ONE
    }
    __shared__ float rs[256]; __shared__ int rc[256];
    rs[tid] = s; rc[tid] = c; __syncthreads();
    for (int st = 128; st > 0; st >>= 1) {
        if (tid < st) { rs[tid] += rs[tid + st]; rc[tid] += rc[tid + st]; }
        __syncthreads();
    }
    if (tid == 0) {
        if (rs[0] != 0.f) atomicAdd(&cnt_f[3], rs[0]);
        if (rc[0])        atomicAdd(&cnt_i[4], rc[0]);
    }
    VMEM_DRAIN();   // my partial sums are at the coherence point
    if (tid == 0 &&
        __hip_atomic_fetch_add((unsigned*)&cnt_i[13], 1u,
            __ATOMIC_RELAXED, SCOPE_AGENT) == (unsigned)(gridDim.x - 1)) {
        int np = aload_i(&cnt_i[0]);
        int nn = aload_i(&cnt_i[4]);
        float f1 = aload_f(&cnt_f[1]);
        float f2 = aload_f(&cnt_f[2]);
        float f3 = aload_f(&cnt_f[3]);
        out[0] = f1 / (float)max(np, 1);
        out[1] = (f2 + f3) / (float)max(np + nn, 1);
    }
}

extern "C" void kernel_launch(void* const* d_in, const int* in_sizes, int n_in,
                              void* d_out, int out_size, void* d_ws, size_t ws_size,
                              hipStream_t stream) {
    const float* loc    = (const float*)d_in[0];
    const float* conf   = (const float*)d_in[1];
    const float* priors = (const float*)d_in[2];
    const float* gt     = (const float*)d_in[3];
    const int*   labels = (const int*)d_in[4];
    float* out = (float*)d_out;
    int*      wi = (int*)d_ws;
    float*    wf = (float*)d_ws;
    unsigned* wu = (unsigned*)d_ws;
    unsigned long long* wbp = (unsigned long long*)(wi + W_BP);

    hipMemsetAsync(d_ws, 0, MEMSET_BYTES, stream);  // counters + hists + bp
    k_best_prior<<<dim3(NOBJ, BB, BPSPLIT), 256, 0, stream>>>(priors, gt, wbp);
    k_match<<<dim3((PP + 255) / 256, BB), 256, 0, stream>>>(
        loc, priors, gt, labels, wbp, wi + W_CONF, wf, wi);
    k_conf<<<CONFBLK, RPB, 0, stream>>>(conf, wi + W_CONF, wu + W_KEY,
                                        wf + W_CE, wf);
    k_histA<<<HISTBLK, 256, 0, stream>>>(wu + W_KEY, wu + W_HA);
    k_histB<<<HISTBLK, 256, 0, stream>>>(wu + W_KEY, wi, wu + W_HA, wu + W_HB);
    k_histC<<<HISTBLK, 256, 0, stream>>>(wu + W_KEY, wi, wu + W_HA, wu + W_HB,
                                         wu + W_HC);
    k_negsum<<<NEGBLK, 256, 0, stream>>>(wu + W_KEY, wf + W_CE, wi, wf,
                                         wu + W_HA, wu + W_HB, wu + W_HC, out);
}

// Round 12
// 370.935 us; speedup vs baseline: 1.3188x; 1.0031x over previous
//
#include <hip/hip_runtime.h>
#include <math.h>

#define BB 8
#define PP 57744
#define NOBJ 20
#define CC 81
#define ROWS (BB*PP)
#define CONFBLK ((ROWS + 255) / 256)   // 1805 blocks, 256 threads, 1 row/lane
#define BPSPLIT 16
#define BPCHUNK ((PP + BPSPLIT - 1) / BPSPLIT)   // 3609
#define HISTBLK 512
#define NEGBLK 512

// ws layout in 4-byte units
// cnt: [0]=num_pos [1]=sl1_sum(f) [2]=pos_ce(f) [3]=neg_ce(f) [4]=neg_cnt
//      [5]=eqCtr [13]=negsum_done
#define W_CNT  0                        // 64 words
#define W_HA   64                       // 8 copies x 2048 bins (bits 31:21)
#define W_HB   (W_HA + 8*2048)          // 8 copies x 2048 (bits 20:10)
#define W_HC   (W_HB + 8*2048)          // 8 copies x 1024 (bits 9:0)
#define W_BP   (W_HC + 8*1024)          // word 41024 (byte 164096, 8-aligned)
#define W_CONF (W_BP + 320)             // ROWS ints
#define W_KEY  (W_CONF + ROWS)          // ROWS uints
#define W_CE   (W_KEY + ROWS)           // ROWS floats
#define MEMSET_BYTES (W_CONF * 4)       // counters + hists + bp

#define SCOPE_AGENT __HIP_MEMORY_SCOPE_AGENT
// Completion ordering only (no buffer_wbl2/buffer_inv cache maintenance —
// the round-5 410us lesson): prior vmem ops retired at the coherence point.
#define VMEM_DRAIN() asm volatile("s_waitcnt vmcnt(0) lgkmcnt(0)" ::: "memory")

__device__ __forceinline__ unsigned keymap(float f) {
    unsigned u = __float_as_uint(f);
    return (u & 0x80000000u) ? ~u : (u | 0x80000000u);
}

__device__ __forceinline__ float smooth_l1(float d) {
    float a = fabsf(d);
    return a < 1.f ? 0.5f * d * d : a - 0.5f;
}

__device__ __forceinline__ int aload_i(const int* p) {
    return __hip_atomic_load(p, __ATOMIC_RELAXED, SCOPE_AGENT);
}
__device__ __forceinline__ float aload_f(const float* p) {
    return __hip_atomic_load(p, __ATOMIC_RELAXED, SCOPE_AGENT);
}

// Descending-cumulative threshold search over NB bins summed across 8 global
// copies, plain cached loads (hist written by a PRIOR kernel; dispatch
// boundaries provide coherence). Deterministic -> every block recomputes it.
template <int NB>
__device__ int scan_bins(const unsigned* __restrict__ h, unsigned Kr,
                         unsigned* rem_out) {
    constexpr int BPT = NB / 256;
    __shared__ unsigned stot[256];
    __shared__ int sbin;
    __shared__ unsigned srem;
    __syncthreads();                 // protect shared reuse across calls
    int i = threadIdx.x & 255;
    unsigned v[BPT];
    unsigned tot = 0;
    #pragma unroll
    for (int j = 0; j < BPT; j++) {
        unsigned s = 0;
        #pragma unroll
        for (int c = 0; c < 8; c++) s += h[c * NB + i * BPT + j];
        v[j] = s; tot += s;
    }
    if (threadIdx.x == 0) sbin = -1;
    if (threadIdx.x < 256) stot[i] = tot;
    __syncthreads();
    if (threadIdx.x < 256) {
        for (int off = 1; off < 256; off <<= 1) {   // inclusive suffix scan
            unsigned add = (i + off < 256) ? stot[i + off] : 0u;
            __syncthreads(); stot[i] += add; __syncthreads();
        }
        unsigned cum = (i < 255) ? stot[i + 1] : 0u;
        #pragma unroll
        for (int j = BPT - 1; j >= 0; j--) {
            unsigned nxt = cum;      // suffix(bin+1)
            cum += v[j];             // suffix(bin)
            if (cum >= Kr && nxt < Kr) { sbin = i * BPT + j; srem = Kr - nxt; }
        }
    } else {
        for (int off = 1; off < 256; off <<= 1) { __syncthreads(); __syncthreads(); }
    }
    __syncthreads();
    *rem_out = (sbin >= 0) ? srem : 0u;
    return sbin;
}

// Grid (NOBJ, BB, BPSPLIT): per-(gt,batch) argmax over a prior chunk, packed
// (iou_bits<<32)|(~p) so u64 max == (max iou, lowest prior idx).
__global__ void k_best_prior(const float* __restrict__ priors,
                             const float* __restrict__ gt,
                             unsigned long long* __restrict__ bp) {
    int n = blockIdx.x, b = blockIdx.y;
    int p0 = blockIdx.z * BPCHUNK;
    int p1 = min(p0 + BPCHUNK, PP);
    const float* t = gt + (b * NOBJ + n) * 4;
    float tx1 = t[0], ty1 = t[1], tx2 = t[2], ty2 = t[3];
    float ta = (tx2 - tx1) * (ty2 - ty1);
    unsigned long long best = 0ull;
    for (int p = p0 + threadIdx.x; p < p1; p += 256) {
        float4 pr = ((const float4*)priors)[p];
        float px1 = pr.x - pr.z * 0.5f, py1 = pr.y - pr.w * 0.5f;
        float px2 = pr.x + pr.z * 0.5f, py2 = pr.y + pr.w * 0.5f;
        float iw = fmaxf(fminf(tx2, px2) - fmaxf(tx1, px1), 0.f);
        float ih = fmaxf(fminf(ty2, py2) - fmaxf(ty1, py1), 0.f);
        float inter = iw * ih;
        float iou = inter / (ta + (px2 - px1) * (py2 - py1) - inter);
        unsigned long long pk = ((unsigned long long)__float_as_uint(iou) << 32)
                              | (unsigned long long)(0xFFFFFFFFu - (unsigned)p);
        if (pk > best) best = pk;
    }
    __shared__ unsigned long long sb[256];
    int tid = threadIdx.x;
    sb[tid] = best; __syncthreads();
    for (int s = 128; s > 0; s >>= 1) {
        if (tid < s && sb[tid + s] > sb[tid]) sb[tid] = sb[tid + s];
        __syncthreads();
    }
    if (tid == 0) atomicMax(&bp[b * NOBJ + n], sb[0]);
}

// Per prior: best truth (argmax over 20, tie->first), force-match (last gt wins),
// conf_t, and smooth-L1 loc loss for positives.
__global__ void k_match(const float* __restrict__ loc_data,
                        const float* __restrict__ priors,
                        const float* __restrict__ gt,
                        const int* __restrict__ labels,
                        const unsigned long long* __restrict__ bp,
                        int* __restrict__ conf_t,
                        float* __restrict__ cnt_f,
                        int* __restrict__ cnt_i) {
    int b = blockIdx.y;
    int tid = threadIdx.x;
    int p = blockIdx.x * 256 + tid;
    __shared__ float st[NOBJ][4];
    __shared__ int slab[NOBJ], sbp[NOBJ];
    if (tid < NOBJ * 4) ((float*)st)[tid] = gt[b * NOBJ * 4 + tid];
    if (tid < NOBJ) {
        slab[tid] = labels[b * NOBJ + tid];
        sbp[tid] = (int)(0xFFFFFFFFu - (unsigned)bp[b * NOBJ + tid]);
    }
    __syncthreads();
    float s_l1 = 0.f; int is_pos = 0;
    if (p < PP) {
        float4 pr = ((const float4*)priors)[p];
        float px1 = pr.x - pr.z * 0.5f, py1 = pr.y - pr.w * 0.5f;
        float px2 = pr.x + pr.z * 0.5f, py2 = pr.y + pr.w * 0.5f;
        float pa = (px2 - px1) * (py2 - py1);
        float best = -1.f; int bn = 0;
        for (int n = 0; n < NOBJ; n++) {
            float tx1 = st[n][0], ty1 = st[n][1], tx2 = st[n][2], ty2 = st[n][3];
            float iw = fmaxf(fminf(tx2, px2) - fmaxf(tx1, px1), 0.f);
            float ih = fmaxf(fminf(ty2, py2) - fmaxf(ty1, py1), 0.f);
            float inter = iw * ih;
            float iou = inter / ((tx2 - tx1) * (ty2 - ty1) + pa - inter);
            if (iou > best) { best = iou; bn = n; }  // tie -> first n
        }
        float ov = best;
        for (int n = 0; n < NOBJ; n++)
            if (sbp[n] == p) { bn = n; ov = 2.0f; }  // last n wins
        int conf = slab[bn];
        if (ov < 0.5f) conf = -1;
        if (ov < 0.4f) conf = 0;
        conf_t[b * PP + p] = conf;
        if (conf > 0) {
            is_pos = 1;
            float mx1 = st[bn][0], my1 = st[bn][1], mx2 = st[bn][2], my2 = st[bn][3];
            float gcx = ((mx1 + mx2) * 0.5f - pr.x) / (0.1f * pr.z);
            float gcy = ((my1 + my2) * 0.5f - pr.y) / (0.1f * pr.w);
            float gw = logf((mx2 - mx1) / pr.z) / 0.2f;
            float gh = logf((my2 - my1) / pr.w) / 0.2f;
            float4 ld = ((const float4*)loc_data)[b * PP + p];
            s_l1 = smooth_l1(ld.x - gcx) + smooth_l1(ld.y - gcy) +
                   smooth_l1(ld.z - gw) + smooth_l1(ld.w - gh);
        }
    }
    __shared__ float rs[256]; __shared__ int rc[256];
    rs[tid] = s_l1; rc[tid] = is_pos; __syncthreads();
    for (int s = 128; s > 0; s >>= 1) {
        if (tid < s) { rs[tid] += rs[tid + s]; rc[tid] += rc[tid + s]; }
        __syncthreads();
    }
    if (tid == 0) {
        if (rs[0] != 0.f) atomicAdd(&cnt_f[1], rs[0]);
        if (rc[0])        atomicAdd(&cnt_i[0], rc[0]);
    }
}

// ROW-PER-LANE, NO LDS: each lane reads its own row straight from global
// (20 x 16B memcpy-float4 + scalar tail; row bases are 4B-aligned — gfx9+
// supports dword-aligned dwordx4). A wave's 64 rows span one contiguous
// 20.7KB region: same cache lines as the old coalesced stage, fetched once,
// L1-served for later offsets. Row lives in registers (no runtime indexing —
// x[ctc] is re-fetched from global/L1 to avoid the scratch trap). No LDS ->
// residency is VGPR-capped (~16 waves/CU vs 7 for the r11 LDS version whose
// 101us was 95% occupancy-stall). No __syncthreads anywhere.
__global__ void __launch_bounds__(256) k_conf(const float* __restrict__ conf_data,
                                              const int* __restrict__ conf_t,
                                              unsigned* __restrict__ key,
                                              float* __restrict__ ce,
                                              float* __restrict__ cnt_f) {
    int row = blockIdx.x * 256 + threadIdx.x;
    bool act = row < ROWS;
    int rr = act ? row : ROWS - 1;
    const float* x = conf_data + (size_t)rr * CC;
    int ct = conf_t[rr];

    float4 v[20];
    #pragma unroll
    for (int j = 0; j < 20; j++) __builtin_memcpy(&v[j], x + 4 * j, 16);
    float x80 = x[80];

    // fg = max over classes 1..80 (4 accumulators for ILP)
    float f0 = v[0].y, f1 = v[0].z, f2 = v[0].w, f3 = x80;
    #pragma unroll
    for (int j = 1; j < 20; j++) {
        f0 = fmaxf(f0, v[j].x);
        f1 = fmaxf(f1, v[j].y);
        f2 = fmaxf(f2, v[j].z);
        f3 = fmaxf(f3, v[j].w);
    }
    float fg = fmaxf(fmaxf(f0, f1), fmaxf(f2, f3));
    float m = fmaxf(fg, v[0].x);

    const float LOG2E = 1.4426950408889634f;
    float e0 = 0.f, e1 = 0.f, e2 = 0.f, e3 = 0.f;
    #pragma unroll
    for (int j = 0; j < 20; j++) {
        e0 += exp2f((v[j].x - m) * LOG2E);
        e1 += exp2f((v[j].y - m) * LOG2E);
        e2 += exp2f((v[j].z - m) * LOG2E);
        e3 += exp2f((v[j].w - m) * LOG2E);
    }
    float e = (e0 + e1) + (e2 + e3) + exp2f((x80 - m) * LOG2E);

    float lse = m + log2f(e) * 0.6931471805599453f;
    int ctc = min(max(ct, 0), CC - 1);
    float xc = x[ctc];               // global re-fetch (L1-hot), not v[ctc]
    float cev = lse - xc;
    if (act) {
        ce[row] = cev;               // coalesced
        key[row] = (ct == 0) ? keymap(fg) : 0u;   // coalesced
        if (ct > 0) atomicAdd(&cnt_f[2], cev);
    }
}

// Level A: 2048-bin LDS histogram of key>>21 (negative candidates = key!=0),
// flushed to 8 spread global copies.
__global__ void __launch_bounds__(256) k_histA(const unsigned* __restrict__ key,
                                               unsigned* __restrict__ hA) {
    __shared__ unsigned lh[2048];
    int tid = threadIdx.x;
    for (int j = tid; j < 2048; j += 256) lh[j] = 0;
    __syncthreads();
    const uint4* k4 = (const uint4*)key;
    int n4 = ROWS / 4;
    for (int r = blockIdx.x * 256 + tid; r < n4; r += gridDim.x * 256) {
        uint4 k = k4[r];
        if (k.x) atomicAdd(&lh[k.x >> 21], 1u);
        if (k.y) atomicAdd(&lh[k.y >> 21], 1u);
        if (k.z) atomicAdd(&lh[k.z >> 21], 1u);
        if (k.w) atomicAdd(&lh[k.w >> 21], 1u);
    }
    __syncthreads();
    unsigned* hmy = hA + (blockIdx.x & 7) * 2048;
    for (int j = tid; j < 2048; j += 256)
        if (lh[j]) atomicAdd(&hmy[j], lh[j]);
}

// Level B: every block recomputes the level-A scan (deterministic, cached
// loads), then histograms bits 20:10 of keys within prefixA.
__global__ void __launch_bounds__(256) k_histB(const unsigned* __restrict__ key,
                                               const int* __restrict__ cnt_i,
                                               const unsigned* __restrict__ hA,
                                               unsigned* __restrict__ hB) {
    unsigned Kr = 3u * (unsigned)cnt_i[0];
    if (Kr == 0) return;                     // negsum handles: select none
    unsigned remB;
    int binA = scan_bins<2048>(hA, Kr, &remB);
    if (binA < 0) return;                    // negsum handles: select all
    unsigned prefixA = (unsigned)binA;

    __shared__ unsigned lh[2048];
    int tid = threadIdx.x;
    for (int j = tid; j < 2048; j += 256) lh[j] = 0;
    __syncthreads();
    const uint4* k4 = (const uint4*)key;
    int n4 = ROWS / 4;
    for (int r = blockIdx.x * 256 + tid; r < n4; r += gridDim.x * 256) {
        uint4 k = k4[r];
        if ((k.x >> 21) == prefixA) atomicAdd(&lh[(k.x >> 10) & 0x7FFu], 1u);
        if ((k.y >> 21) == prefixA) atomicAdd(&lh[(k.y >> 10) & 0x7FFu], 1u);
        if ((k.z >> 21) == prefixA) atomicAdd(&lh[(k.z >> 10) & 0x7FFu], 1u);
        if ((k.w >> 21) == prefixA) atomicAdd(&lh[(k.w >> 10) & 0x7FFu], 1u);
    }
    __syncthreads();
    unsigned* hmy = hB + (blockIdx.x & 7) * 2048;
    for (int j = tid; j < 2048; j += 256)
        if (lh[j]) atomicAdd(&hmy[j], lh[j]);
}

// Level C: recompute scans A and B, then histogram bits 9:0 within prefixAB.
__global__ void __launch_bounds__(256) k_histC(const unsigned* __restrict__ key,
                                               const int* __restrict__ cnt_i,
                                               const unsigned* __restrict__ hA,
                                               const unsigned* __restrict__ hB,
                                               unsigned* __restrict__ hC) {
    unsigned Kr = 3u * (unsigned)cnt_i[0];
    if (Kr == 0) return;
    unsigned remB;
    int binA = scan_bins<2048>(hA, Kr, &remB);
    if (binA < 0) return;
    unsigned remC;
    int binB = scan_bins<2048>(hB, remB, &remC);
    if (binB < 0) { binB = 0; remC = 0; }    // defensive (cannot happen)
    unsigned prefixAB = ((unsigned)binA << 11) | (unsigned)binB;

    __shared__ unsigned lh[1024];
    int tid = threadIdx.x;
    for (int j = tid; j < 1024; j += 256) lh[j] = 0;
    __syncthreads();
    const uint4* k4 = (const uint4*)key;
    int n4 = ROWS / 4;
    for (int r = blockIdx.x * 256 + tid; r < n4; r += gridDim.x * 256) {
        uint4 k = k4[r];
        if ((k.x >> 10) == prefixAB) atomicAdd(&lh[k.x & 0x3FFu], 1u);
        if ((k.y >> 10) == prefixAB) atomicAdd(&lh[k.y & 0x3FFu], 1u);
        if ((k.z >> 10) == prefixAB) atomicAdd(&lh[k.z & 0x3FFu], 1u);
        if ((k.w >> 10) == prefixAB) atomicAdd(&lh[k.w & 0x3FFu], 1u);
    }
    __syncthreads();
    unsigned* hmy = hC + (blockIdx.x & 7) * 1024;
    for (int j = tid; j < 1024; j += 256)
        if (lh[j]) atomicAdd(&hmy[j], lh[j]);
}

// Recompute all three scans (cached loads) -> exact 32-bit threshold T +
// eqSlots, sum CE over selected negatives (candidates = key != 0), and fold
// the final loss computation via the relaxed done-counter + vmcnt(0) publish
// pattern (r6/r7-proven; only place needing same-kernel cross-block data).
__global__ void __launch_bounds__(256) k_negsum(const unsigned* __restrict__ key,
                                                const float* __restrict__ ce,
                                                int* __restrict__ cnt_i,
                                                float* __restrict__ cnt_f,
                                                const unsigned* __restrict__ hA,
                                                const unsigned* __restrict__ hB,
                                                const unsigned* __restrict__ hC,
                                                float* __restrict__ out) {
    int tid = threadIdx.x;
    unsigned Kr = 3u * (unsigned)cnt_i[0];
    unsigned T; int eqS;
    if (Kr == 0) { T = 0xFFFFFFFFu; eqS = 0; }   // no positives: select none
    else {
        unsigned remB;
        int binA = scan_bins<2048>(hA, Kr, &remB);
        if (binA < 0) { T = 0u; eqS = 0; }       // total < Kr: select all
        else {
            unsigned remC;
            int binB = scan_bins<2048>(hB, remB, &remC);
            if (binB < 0) { binB = 0; remC = 0; }
            unsigned remD;
            int binC = scan_bins<1024>(hC, remC, &remD);
            if (binC < 0) { binC = 0; remD = 0; }
            T = ((unsigned)binA << 21) | ((unsigned)binB << 10) | (unsigned)binC;
            eqS = (int)remD;
        }
    }

    float s = 0.f; int c = 0;
    const uint4* k4 = (const uint4*)key;
    int n4 = ROWS / 4;
    for (int r = blockIdx.x * 256 + tid; r < n4; r += gridDim.x * 256) {
        uint4 k = k4[r];
        #define DO_ONE(comp, idx) { \
            unsigned kk = k.comp; \
            if (kk) { \
                bool selr = false; \
                if (kk > T) selr = true; \
                else if (kk == T) { int slot = atomicAdd(&cnt_i[5], 1); selr = slot < eqS; } \
                if (selr) { s += ce[4 * r + idx]; c++; } \
            } }
        DO_ONE(x, 0) DO_ONE(y, 1) DO_ONE(z, 2) DO_ONE(w, 3)
        #undef DO_ONE
    }
    __shared__ float rs[256]; __shared__ int rc[256];
    rs[tid] = s; rc[tid] = c; __syncthreads();
    for (int st = 128; st > 0; st >>= 1) {
        if (tid < st) { rs[tid] += rs[tid + st]; rc[tid] += rc[tid + st]; }
        __syncthreads();
    }
    if (tid == 0) {
        if (rs[0] != 0.f) atomicAdd(&cnt_f[3], rs[0]);
        if (rc[0])        atomicAdd(&cnt_i[4], rc[0]);
    }
    VMEM_DRAIN();   // my partial sums are at the coherence point
    if (tid == 0 &&
        __hip_atomic_fetch_add((unsigned*)&cnt_i[13], 1u,
            __ATOMIC_RELAXED, SCOPE_AGENT) == (unsigned)(gridDim.x - 1)) {
        int np = aload_i(&cnt_i[0]);
        int nn = aload_i(&cnt_i[4]);
        float f1 = aload_f(&cnt_f[1]);
        float f2 = aload_f(&cnt_f[2]);
        float f3 = aload_f(&cnt_f[3]);
        out[0] = f1 / (float)max(np, 1);
        out[1] = (f2 + f3) / (float)max(np + nn, 1);
    }
}

extern "C" void kernel_launch(void* const* d_in, const int* in_sizes, int n_in,
                              void* d_out, int out_size, void* d_ws, size_t ws_size,
                              hipStream_t stream) {
    const float* loc    = (const float*)d_in[0];
    const float* conf   = (const float*)d_in[1];
    const float* priors = (const float*)d_in[2];
    const float* gt     = (const float*)d_in[3];
    const int*   labels = (const int*)d_in[4];
    float* out = (float*)d_out;
    int*      wi = (int*)d_ws;
    float*    wf = (float*)d_ws;
    unsigned* wu = (unsigned*)d_ws;
    unsigned long long* wbp = (unsigned long long*)(wi + W_BP);

    hipMemsetAsync(d_ws, 0, MEMSET_BYTES, stream);  // counters + hists + bp
    k_best_prior<<<dim3(NOBJ, BB, BPSPLIT), 256, 0, stream>>>(priors, gt, wbp);
    k_match<<<dim3((PP + 255) / 256, BB), 256, 0, stream>>>(
        loc, priors, gt, labels, wbp, wi + W_CONF, wf, wi);
    k_conf<<<CONFBLK, 256, 0, stream>>>(conf, wi + W_CONF, wu + W_KEY,
                                        wf + W_CE, wf);
    k_histA<<<HISTBLK, 256, 0, stream>>>(wu + W_KEY, wu + W_HA);
    k_histB<<<HISTBLK, 256, 0, stream>>>(wu + W_KEY, wi, wu + W_HA, wu + W_HB);
    k_histC<<<HISTBLK, 256, 0, stream>>>(wu + W_KEY, wi, wu + W_HA, wu + W_HB,
                                         wu + W_HC);
    k_negsum<<<NEGBLK, 256, 0, stream>>>(wu + W_KEY, wf + W_CE, wi, wf,
                                         wu + W_HA, wu + W_HB, wu + W_HC, out);
}

// Round 13
// 368.686 us; speedup vs baseline: 1.3268x; 1.0061x over previous
//
#include <hip/hip_runtime.h>
#include <math.h>

#define BB 8
#define PP 57744
#define NOBJ 20
#define CC 81
#define ROWS (BB*PP)
#define CONFBLK ((ROWS + 255) / 256)   // 1805 blocks, 256 threads, 1 row/lane
#define BPSPLIT 16
#define BPCHUNK ((PP + BPSPLIT - 1) / BPSPLIT)   // 3609
#define SELBLK 256   // co-resident (4-wave, 8KB-LDS blocks; capacity >> 256)

// ws layout in 4-byte units
// cnt: [0]=num_pos [1]=sl1_sum(f) [2]=pos_ce(f) [3]=neg_ce(f) [4]=neg_cnt
//      [5]=eqCtr [10]=T [11]=eqSlots [12]=doneB [13]=negsum_done [14]=flagB
//      [15]=prefixAB [16]=KrC [17]=doneC [21]=flagD
#define W_CNT  0                        // 64 words
#define W_HA   64                       // 8 copies x 2048 bins (bits 31:21)
#define W_HB   (W_HA + 8*2048)          // 8 copies x 2048 (bits 20:10)
#define W_HC   (W_HB + 8*2048)          // 8 copies x 1024 (bits 9:0)
#define W_BP   (W_HC + 8*1024)          // word 41024 (byte 164096, 8-aligned)
#define W_CONF (W_BP + 320)             // ROWS ints
#define W_KEY  (W_CONF + ROWS)          // ROWS uints
#define W_CE   (W_KEY + ROWS)           // ROWS floats
#define MEMSET_BYTES (W_CONF * 4)       // counters + hists + bp

#define SCOPE_AGENT __HIP_MEMORY_SCOPE_AGENT
// Completion ordering only (no buffer_wbl2/buffer_inv cache maintenance —
// the round-5 410us lesson): prior vmem ops retired at the coherence point.
#define VMEM_DRAIN() asm volatile("s_waitcnt vmcnt(0) lgkmcnt(0)" ::: "memory")

__device__ __forceinline__ unsigned keymap(float f) {
    unsigned u = __float_as_uint(f);
    return (u & 0x80000000u) ? ~u : (u | 0x80000000u);
}

__device__ __forceinline__ float smooth_l1(float d) {
    float a = fabsf(d);
    return a < 1.f ? 0.5f * d * d : a - 0.5f;
}

__device__ __forceinline__ unsigned aload_u(const unsigned* p) {
    return __hip_atomic_load(p, __ATOMIC_RELAXED, SCOPE_AGENT);
}
__device__ __forceinline__ int aload_i(const int* p) {
    return __hip_atomic_load(p, __ATOMIC_RELAXED, SCOPE_AGENT);
}
__device__ __forceinline__ float aload_f(const float* p) {
    return __hip_atomic_load(p, __ATOMIC_RELAXED, SCOPE_AGENT);
}
__device__ __forceinline__ void astore_i(int* p, int v) {
    __hip_atomic_store(p, v, __ATOMIC_RELAXED, SCOPE_AGENT);
}

// Descending-cumulative threshold search over NB bins summed across 8 global
// copies. ATOMIC=false: plain cached loads — ONLY valid when the hist was
// written by a PRIOR kernel (dispatch boundary = coherence). ATOMIC=true:
// agent-scope loads — required when reading same-kernel writes (k_sel's
// last-block scans). Deterministic given identical inputs.
template <int NB, bool ATOMIC>
__device__ int scan_bins(const unsigned* __restrict__ h, unsigned Kr,
                         unsigned* rem_out) {
    constexpr int BPT = NB / 256;
    __shared__ unsigned stot[256];
    __shared__ int sbin;
    __shared__ unsigned srem;
    __syncthreads();                 // protect shared reuse across calls
    int i = threadIdx.x;
    unsigned v[BPT];
    unsigned tot = 0;
    #pragma unroll
    for (int j = 0; j < BPT; j++) {
        unsigned s = 0;
        #pragma unroll
        for (int c = 0; c < 8; c++) {
            const unsigned* p = h + c * NB + i * BPT + j;
            s += ATOMIC ? aload_u(p) : *p;
        }
        v[j] = s; tot += s;
    }
    if (i == 0) sbin = -1;
    stot[i] = tot; __syncthreads();
    for (int off = 1; off < 256; off <<= 1) {   // inclusive suffix scan
        unsigned add = (i + off < 256) ? stot[i + off] : 0u;
        __syncthreads(); stot[i] += add; __syncthreads();
    }
    unsigned cum = (i < 255) ? stot[i + 1] : 0u;
    #pragma unroll
    for (int j = BPT - 1; j >= 0; j--) {
        unsigned nxt = cum;      // suffix(bin+1)
        cum += v[j];             // suffix(bin)
        if (cum >= Kr && nxt < Kr) { sbin = i * BPT + j; srem = Kr - nxt; }
    }
    __syncthreads();
    *rem_out = (sbin >= 0) ? srem : 0u;
    return sbin;
}

// Grid (NOBJ, BB, BPSPLIT): per-(gt,batch) argmax over a prior chunk, packed
// (iou_bits<<32)|(~p) so u64 max == (max iou, lowest prior idx).
__global__ void k_best_prior(const float* __restrict__ priors,
                             const float* __restrict__ gt,
                             unsigned long long* __restrict__ bp) {
    int n = blockIdx.x, b = blockIdx.y;
    int p0 = blockIdx.z * BPCHUNK;
    int p1 = min(p0 + BPCHUNK, PP);
    const float* t = gt + (b * NOBJ + n) * 4;
    float tx1 = t[0], ty1 = t[1], tx2 = t[2], ty2 = t[3];
    float ta = (tx2 - tx1) * (ty2 - ty1);
    unsigned long long best = 0ull;
    for (int p = p0 + threadIdx.x; p < p1; p += 256) {
        float4 pr = ((const float4*)priors)[p];
        float px1 = pr.x - pr.z * 0.5f, py1 = pr.y - pr.w * 0.5f;
        float px2 = pr.x + pr.z * 0.5f, py2 = pr.y + pr.w * 0.5f;
        float iw = fmaxf(fminf(tx2, px2) - fmaxf(tx1, px1), 0.f);
        float ih = fmaxf(fminf(ty2, py2) - fmaxf(ty1, py1), 0.f);
        float inter = iw * ih;
        float iou = inter / (ta + (px2 - px1) * (py2 - py1) - inter);
        unsigned long long pk = ((unsigned long long)__float_as_uint(iou) << 32)
                              | (unsigned long long)(0xFFFFFFFFu - (unsigned)p);
        if (pk > best) best = pk;
    }
    __shared__ unsigned long long sb[256];
    int tid = threadIdx.x;
    sb[tid] = best; __syncthreads();
    for (int s = 128; s > 0; s >>= 1) {
        if (tid < s && sb[tid + s] > sb[tid]) sb[tid] = sb[tid + s];
        __syncthreads();
    }
    if (tid == 0) atomicMax(&bp[b * NOBJ + n], sb[0]);
}

// Per prior: best truth (argmax over 20, tie->first), force-match (last gt wins),
// conf_t, and smooth-L1 loc loss for positives.
__global__ void k_match(const float* __restrict__ loc_data,
                        const float* __restrict__ priors,
                        const float* __restrict__ gt,
                        const int* __restrict__ labels,
                        const unsigned long long* __restrict__ bp,
                        int* __restrict__ conf_t,
                        float* __restrict__ cnt_f,
                        int* __restrict__ cnt_i) {
    int b = blockIdx.y;
    int tid = threadIdx.x;
    int p = blockIdx.x * 256 + tid;
    __shared__ float st[NOBJ][4];
    __shared__ int slab[NOBJ], sbp[NOBJ];
    if (tid < NOBJ * 4) ((float*)st)[tid] = gt[b * NOBJ * 4 + tid];
    if (tid < NOBJ) {
        slab[tid] = labels[b * NOBJ + tid];
        sbp[tid] = (int)(0xFFFFFFFFu - (unsigned)bp[b * NOBJ + tid]);
    }
    __syncthreads();
    float s_l1 = 0.f; int is_pos = 0;
    if (p < PP) {
        float4 pr = ((const float4*)priors)[p];
        float px1 = pr.x - pr.z * 0.5f, py1 = pr.y - pr.w * 0.5f;
        float px2 = pr.x + pr.z * 0.5f, py2 = pr.y + pr.w * 0.5f;
        float pa = (px2 - px1) * (py2 - py1);
        float best = -1.f; int bn = 0;
        for (int n = 0; n < NOBJ; n++) {
            float tx1 = st[n][0], ty1 = st[n][1], tx2 = st[n][2], ty2 = st[n][3];
            float iw = fmaxf(fminf(tx2, px2) - fmaxf(tx1, px1), 0.f);
            float ih = fmaxf(fminf(ty2, py2) - fmaxf(ty1, py1), 0.f);
            float inter = iw * ih;
            float iou = inter / ((tx2 - tx1) * (ty2 - ty1) + pa - inter);
            if (iou > best) { best = iou; bn = n; }  // tie -> first n
        }
        float ov = best;
        for (int n = 0; n < NOBJ; n++)
            if (sbp[n] == p) { bn = n; ov = 2.0f; }  // last n wins
        int conf = slab[bn];
        if (ov < 0.5f) conf = -1;
        if (ov < 0.4f) conf = 0;
        conf_t[b * PP + p] = conf;
        if (conf > 0) {
            is_pos = 1;
            float mx1 = st[bn][0], my1 = st[bn][1], mx2 = st[bn][2], my2 = st[bn][3];
            float gcx = ((mx1 + mx2) * 0.5f - pr.x) / (0.1f * pr.z);
            float gcy = ((my1 + my2) * 0.5f - pr.y) / (0.1f * pr.w);
            float gw = logf((mx2 - mx1) / pr.z) / 0.2f;
            float gh = logf((my2 - my1) / pr.w) / 0.2f;
            float4 ld = ((const float4*)loc_data)[b * PP + p];
            s_l1 = smooth_l1(ld.x - gcx) + smooth_l1(ld.y - gcy) +
                   smooth_l1(ld.z - gw) + smooth_l1(ld.w - gh);
        }
    }
    __shared__ float rs[256]; __shared__ int rc[256];
    rs[tid] = s_l1; rc[tid] = is_pos; __syncthreads();
    for (int s = 128; s > 0; s >>= 1) {
        if (tid < s) { rs[tid] += rs[tid + s]; rc[tid] += rc[tid + s]; }
        __syncthreads();
    }
    if (tid == 0) {
        if (rs[0] != 0.f) atomicAdd(&cnt_f[1], rs[0]);
        if (rc[0])        atomicAdd(&cnt_i[0], rc[0]);
    }
}

// ROW-PER-LANE, NO LDS staging (r12, ~100us) + FUSED level-A histogram:
// per-block 2048-bin LDS hist of key>>21 (LDS atomics; ~50-200 hot bins),
// flushed once per block to 8 spread global copies (r3/r4-proven pattern).
// Saves the separate k_histA launch + one full key pass.
__global__ void __launch_bounds__(256) k_conf(const float* __restrict__ conf_data,
                                              const int* __restrict__ conf_t,
                                              unsigned* __restrict__ key,
                                              float* __restrict__ ce,
                                              float* __restrict__ cnt_f,
                                              unsigned* __restrict__ hA) {
    __shared__ unsigned lhist[2048];
    int tid = threadIdx.x;
    for (int j = tid; j < 2048; j += 256) lhist[j] = 0;
    __syncthreads();

    int row = blockIdx.x * 256 + tid;
    bool act = row < ROWS;
    int rr = act ? row : ROWS - 1;
    const float* x = conf_data + (size_t)rr * CC;
    int ct = conf_t[rr];

    float4 v[20];
    #pragma unroll
    for (int j = 0; j < 20; j++) __builtin_memcpy(&v[j], x + 4 * j, 16);
    float x80 = x[80];

    // fg = max over classes 1..80 (4 accumulators for ILP)
    float f0 = v[0].y, f1 = v[0].z, f2 = v[0].w, f3 = x80;
    #pragma unroll
    for (int j = 1; j < 20; j++) {
        f0 = fmaxf(f0, v[j].x);
        f1 = fmaxf(f1, v[j].y);
        f2 = fmaxf(f2, v[j].z);
        f3 = fmaxf(f3, v[j].w);
    }
    float fg = fmaxf(fmaxf(f0, f1), fmaxf(f2, f3));
    float m = fmaxf(fg, v[0].x);

    const float LOG2E = 1.4426950408889634f;
    float e0 = 0.f, e1 = 0.f, e2 = 0.f, e3 = 0.f;
    #pragma unroll
    for (int j = 0; j < 20; j++) {
        e0 += exp2f((v[j].x - m) * LOG2E);
        e1 += exp2f((v[j].y - m) * LOG2E);
        e2 += exp2f((v[j].z - m) * LOG2E);
        e3 += exp2f((v[j].w - m) * LOG2E);
    }
    float e = (e0 + e1) + (e2 + e3) + exp2f((x80 - m) * LOG2E);

    float lse = m + log2f(e) * 0.6931471805599453f;
    int ctc = min(max(ct, 0), CC - 1);
    float xc = x[ctc];               // global re-fetch (L1-hot), not v[ctc]
    float cev = lse - xc;
    if (act) {
        ce[row] = cev;
        unsigned kv = (ct == 0) ? keymap(fg) : 0u;
        key[row] = kv;
        if (ct > 0) atomicAdd(&cnt_f[2], cev);
        if (ct == 0) atomicAdd(&lhist[kv >> 21], 1u);
    }
    __syncthreads();
    unsigned* hmy = hA + (blockIdx.x & 7) * 2048;
    for (int j = tid; j < 2048; j += 256)
        if (lhist[j]) atomicAdd(&hmy[j], lhist[j]);
}

// Fused selection: scan-A (per-block, plain loads on prior-kernel hA) ->
// phase-B hist -> last-block scan+publish -> phase-C hist -> last-block
// scan+publish -> negative-CE sum -> fused final. Cross-block sync uses ONLY
// relaxed agent atomics + vmcnt(0) completion (r6/r7-proven); last-block
// scans of SAME-KERNEL hists use agent-scope loads (ATOMIC=true); the r6
// regression (threadfence cache-maintenance + all-block agent-load scans)
// is avoided. SELBLK=256 co-resident blocks -> spins cannot deadlock.
__global__ void __launch_bounds__(256) k_sel(const unsigned* __restrict__ key,
                                             const float* __restrict__ ce,
                                             int* __restrict__ cnt_i,
                                             float* __restrict__ cnt_f,
                                             const unsigned* __restrict__ hA,
                                             unsigned* __restrict__ hB,
                                             unsigned* __restrict__ hC,
                                             float* __restrict__ out) {
    __shared__ unsigned lh[2048];
    __shared__ int amLast;
    int tid = threadIdx.x;
    const uint4* k4 = (const uint4*)key;
    int n4 = ROWS / 4;

    unsigned T = 0xFFFFFFFFu; int eqS = 0;
    unsigned Kr = 3u * (unsigned)cnt_i[0];
    bool decided = (Kr == 0);            // no positives: select none
    unsigned prefixA = 0, remB = 0;
    if (!decided) {
        int binA = scan_bins<2048, false>(hA, Kr, &remB);
        if (binA < 0) { T = 0u; eqS = 0; decided = true; }  // select all
        else prefixA = (unsigned)binA;
    }

    if (!decided) {
        // ---- phase B: bits 20:10 within prefixA ----
        for (int j = tid; j < 2048; j += 256) lh[j] = 0;
        __syncthreads();
        for (int r = blockIdx.x * 256 + tid; r < n4; r += gridDim.x * 256) {
            uint4 k = k4[r];
            if ((k.x >> 21) == prefixA) atomicAdd(&lh[(k.x >> 10) & 0x7FFu], 1u);
            if ((k.y >> 21) == prefixA) atomicAdd(&lh[(k.y >> 10) & 0x7FFu], 1u);
            if ((k.z >> 21) == prefixA) atomicAdd(&lh[(k.z >> 10) & 0x7FFu], 1u);
            if ((k.w >> 21) == prefixA) atomicAdd(&lh[(k.w >> 10) & 0x7FFu], 1u);
        }
        __syncthreads();
        {
            unsigned* hmy = hB + (blockIdx.x & 7) * 2048;
            for (int j = tid; j < 2048; j += 256)
                if (lh[j]) atomicAdd(&hmy[j], lh[j]);
        }
        VMEM_DRAIN();
        if (tid == 0)
            amLast = (__hip_atomic_fetch_add((unsigned*)&cnt_i[12], 1u,
                       __ATOMIC_RELAXED, SCOPE_AGENT) == (unsigned)(gridDim.x - 1));
        __syncthreads();
        if (amLast) {
            unsigned remC; int binB = scan_bins<2048, true>(hB, remB, &remC);
            if (binB < 0) { binB = 0; remC = 0; }   // defensive
            if (tid == 0) {
                astore_i(&cnt_i[15], (int)((prefixA << 11) | (unsigned)binB));
                astore_i(&cnt_i[16], (int)remC);
                VMEM_DRAIN();
                astore_i(&cnt_i[14], 1);  // flagB
            }
        }
        if (tid == 0) {
            while (aload_i(&cnt_i[14]) == 0) __builtin_amdgcn_s_sleep(8);
        }
        __syncthreads();
        unsigned prefixAB = (unsigned)aload_i(&cnt_i[15]);
        unsigned KrC = (unsigned)aload_i(&cnt_i[16]);

        // ---- phase C: bits 9:0 within prefixAB ----
        for (int j = tid; j < 1024; j += 256) lh[j] = 0;
        __syncthreads();
        for (int r = blockIdx.x * 256 + tid; r < n4; r += gridDim.x * 256) {
            uint4 k = k4[r];
            if ((k.x >> 10) == prefixAB) atomicAdd(&lh[k.x & 0x3FFu], 1u);
            if ((k.y >> 10) == prefixAB) atomicAdd(&lh[k.y & 0x3FFu], 1u);
            if ((k.z >> 10) == prefixAB) atomicAdd(&lh[k.z & 0x3FFu], 1u);
            if ((k.w >> 10) == prefixAB) atomicAdd(&lh[k.w & 0x3FFu], 1u);
        }
        __syncthreads();
        {
            unsigned* hmy = hC + (blockIdx.x & 7) * 1024;
            for (int j = tid; j < 1024; j += 256)
                if (lh[j]) atomicAdd(&hmy[j], lh[j]);
        }
        VMEM_DRAIN();
        if (tid == 0)
            amLast = (__hip_atomic_fetch_add((unsigned*)&cnt_i[17], 1u,
                       __ATOMIC_RELAXED, SCOPE_AGENT) == (unsigned)(gridDim.x - 1));
        __syncthreads();
        if (amLast) {
            unsigned remD; int binC = scan_bins<1024, true>(hC, KrC, &remD);
            if (binC < 0) { binC = 0; remD = 0; }   // defensive
            if (tid == 0) {
                astore_i(&cnt_i[10], (int)((prefixAB << 10) | (unsigned)binC));
                astore_i(&cnt_i[11], (int)remD);
                VMEM_DRAIN();
                astore_i(&cnt_i[21], 1);  // flagD
            }
        }
        if (tid == 0) {
            while (aload_i(&cnt_i[21]) == 0) __builtin_amdgcn_s_sleep(8);
        }
        __syncthreads();
        T = (unsigned)aload_i(&cnt_i[10]);
        eqS = aload_i(&cnt_i[11]);
    }

    // ---- negative-CE sum over selected (key > T, or == T up to eqS) ----
    float s = 0.f; int c = 0;
    for (int r = blockIdx.x * 256 + tid; r < n4; r += gridDim.x * 256) {
        uint4 k = k4[r];
        #define DO_ONE(comp, idx) { \
            unsigned kk = k.comp; \
            if (kk) { \
                bool selr = false; \
                if (kk > T) selr = true; \
                else if (kk == T) { int slot = atomicAdd(&cnt_i[5], 1); selr = slot < eqS; } \
                if (selr) { s += ce[4 * r + idx]; c++; } \
            } }
        DO_ONE(x, 0) DO_ONE(y, 1) DO_ONE(z, 2) DO_ONE(w, 3)
        #undef DO_ONE
    }
    __shared__ float rs[256]; __shared__ int rc[256];
    rs[tid] = s; rc[tid] = c; __syncthreads();
    for (int st = 128; st > 0; st >>= 1) {
        if (tid < st) { rs[tid] += rs[tid + st]; rc[tid] += rc[tid + st]; }
        __syncthreads();
    }
    if (tid == 0) {
        if (rs[0] != 0.f) atomicAdd(&cnt_f[3], rs[0]);
        if (rc[0])        atomicAdd(&cnt_i[4], rc[0]);
    }
    VMEM_DRAIN();   // my partial sums are at the coherence point
    if (tid == 0 &&
        __hip_atomic_fetch_add((unsigned*)&cnt_i[13], 1u,
            __ATOMIC_RELAXED, SCOPE_AGENT) == (unsigned)(gridDim.x - 1)) {
        int np = aload_i(&cnt_i[0]);
        int nn = aload_i(&cnt_i[4]);
        float f1 = aload_f(&cnt_f[1]);
        float f2 = aload_f(&cnt_f[2]);
        float f3 = aload_f(&cnt_f[3]);
        out[0] = f1 / (float)max(np, 1);
        out[1] = (f2 + f3) / (float)max(np + nn, 1);
    }
}

extern "C" void kernel_launch(void* const* d_in, const int* in_sizes, int n_in,
                              void* d_out, int out_size, void* d_ws, size_t ws_size,
                              hipStream_t stream) {
    const float* loc    = (const float*)d_in[0];
    const float* conf   = (const float*)d_in[1];
    const float* priors = (const float*)d_in[2];
    const float* gt     = (const float*)d_in[3];
    const int*   labels = (const int*)d_in[4];
    float* out = (float*)d_out;
    int*      wi = (int*)d_ws;
    float*    wf = (float*)d_ws;
    unsigned* wu = (unsigned*)d_ws;
    unsigned long long* wbp = (unsigned long long*)(wi + W_BP);

    hipMemsetAsync(d_ws, 0, MEMSET_BYTES, stream);  // counters + hists + bp
    k_best_prior<<<dim3(NOBJ, BB, BPSPLIT), 256, 0, stream>>>(priors, gt, wbp);
    k_match<<<dim3((PP + 255) / 256, BB), 256, 0, stream>>>(
        loc, priors, gt, labels, wbp, wi + W_CONF, wf, wi);
    k_conf<<<CONFBLK, 256, 0, stream>>>(conf, wi + W_CONF, wu + W_KEY,
                                        wf + W_CE, wf, wu + W_HA);
    k_sel<<<SELBLK, 256, 0, stream>>>(wu + W_KEY, wf + W_CE, wi, wf,
                                      wu + W_HA, wu + W_HB, wu + W_HC, out);
}

// Round 14
// 361.111 us; speedup vs baseline: 1.3546x; 1.0210x over previous
//
#include <hip/hip_runtime.h>
#include <math.h>

#define BB 8
#define PP 57744
#define NOBJ 20
#define CC 81
#define ROWS (BB*PP)
#define CONFBLK ((ROWS + 255) / 256)   // 1805 blocks, 256 threads, 1 row/lane
#define BPSPLIT 8
#define BPCHUNK (PP / BPSPLIT)         // 7218 exactly (8*7218 == 57744)
#define SELBLK 128   // co-resident; fewer spin participants than r13's 256

// ws layout in 4-byte units
// cnt: [0]=num_pos [1]=sl1_sum(f) [2]=pos_ce(f) [3]=neg_ce(f) [4]=neg_cnt
//      [5]=eqCtr [10]=T [11]=eqSlots [12]=doneB [13]=negsum_done [14]=flagB
//      [15]=prefixAB [16]=KrC [17]=doneC [21]=flagD
#define W_CNT  0                        // 64 words
#define W_HA   64                       // 8 copies x 2048 bins (bits 31:21)
#define W_HB   (W_HA + 8*2048)          // 8 copies x 2048 (bits 20:10)
#define W_HC   (W_HB + 8*2048)          // 8 copies x 1024 (bits 9:0)
#define W_ZERO (W_HC + 8*1024)          // 41024 words: everything above is
                                        // zeroed by k_best_prior's stripe
#define W_BP   W_ZERO                   // 160*8 u64 slots = 2560 words
                                        // (plain-stored, no init needed)
#define W_CONF (W_BP + 2560)            // ROWS ints
#define W_KEY  (W_CONF + ROWS)          // ROWS uints
#define W_CE   (W_KEY + ROWS)           // ROWS floats

#define SCOPE_AGENT __HIP_MEMORY_SCOPE_AGENT
// Completion ordering only (no buffer_wbl2/buffer_inv cache maintenance —
// the round-5 410us lesson): prior vmem ops retired at the coherence point.
#define VMEM_DRAIN() asm volatile("s_waitcnt vmcnt(0) lgkmcnt(0)" ::: "memory")

__device__ __forceinline__ unsigned keymap(float f) {
    unsigned u = __float_as_uint(f);
    return (u & 0x80000000u) ? ~u : (u | 0x80000000u);
}

__device__ __forceinline__ float smooth_l1(float d) {
    float a = fabsf(d);
    return a < 1.f ? 0.5f * d * d : a - 0.5f;
}

__device__ __forceinline__ unsigned aload_u(const unsigned* p) {
    return __hip_atomic_load(p, __ATOMIC_RELAXED, SCOPE_AGENT);
}
__device__ __forceinline__ int aload_i(const int* p) {
    return __hip_atomic_load(p, __ATOMIC_RELAXED, SCOPE_AGENT);
}
__device__ __forceinline__ float aload_f(const float* p) {
    return __hip_atomic_load(p, __ATOMIC_RELAXED, SCOPE_AGENT);
}
__device__ __forceinline__ void astore_i(int* p, int v) {
    __hip_atomic_store(p, v, __ATOMIC_RELAXED, SCOPE_AGENT);
}

// Descending-cumulative threshold search over NB bins summed across 8 global
// copies. ATOMIC=false: plain cached loads — ONLY valid when the hist was
// written by a PRIOR kernel (dispatch boundary = coherence). ATOMIC=true:
// agent-scope loads — required when reading same-kernel writes (k_sel's
// last-block scans). Deterministic given identical inputs.
template <int NB, bool ATOMIC>
__device__ int scan_bins(const unsigned* __restrict__ h, unsigned Kr,
                         unsigned* rem_out) {
    constexpr int BPT = NB / 256;
    __shared__ unsigned stot[256];
    __shared__ int sbin;
    __shared__ unsigned srem;
    __syncthreads();                 // protect shared reuse across calls
    int i = threadIdx.x;
    unsigned v[BPT];
    unsigned tot = 0;
    #pragma unroll
    for (int j = 0; j < BPT; j++) {
        unsigned s = 0;
        #pragma unroll
        for (int c = 0; c < 8; c++) {
            const unsigned* p = h + c * NB + i * BPT + j;
            s += ATOMIC ? aload_u(p) : *p;
        }
        v[j] = s; tot += s;
    }
    if (i == 0) sbin = -1;
    stot[i] = tot; __syncthreads();
    for (int off = 1; off < 256; off <<= 1) {   // inclusive suffix scan
        unsigned add = (i + off < 256) ? stot[i + off] : 0u;
        __syncthreads(); stot[i] += add; __syncthreads();
    }
    unsigned cum = (i < 255) ? stot[i + 1] : 0u;
    #pragma unroll
    for (int j = BPT - 1; j >= 0; j--) {
        unsigned nxt = cum;      // suffix(bin+1)
        cum += v[j];             // suffix(bin)
        if (cum >= Kr && nxt < Kr) { sbin = i * BPT + j; srem = Kr - nxt; }
    }
    __syncthreads();
    *rem_out = (sbin >= 0) ? srem : 0u;
    return sbin;
}

// Grid (NOBJ, BB, BPSPLIT): per-(gt,batch,chunk) argmax over a prior chunk,
// packed (iou_bits<<32)|(~p). Each block PLAIN-STORES its own slot (written
// exactly once; no atomicMax, no init dependency — poison-safe). Also zeroes
// the cnt+hist regions (bp never touches them; the kernel boundary publishes
// the zeros to match/conf/sel) — replaces the hipMemsetAsync launch.
__global__ void k_best_prior(const float* __restrict__ priors,
                             const float* __restrict__ gt,
                             unsigned long long* __restrict__ bp8,
                             int* __restrict__ ws) {
    int n = blockIdx.x, b = blockIdx.y, z = blockIdx.z;
    // zero stripe: blocks cover W_ZERO words of counters+hists
    int bid = n + NOBJ * (b + BB * z);
    int gz = bid * 256 + threadIdx.x;
    if (gz < W_ZERO) ws[gz] = 0;

    int p0 = z * BPCHUNK;
    int p1 = p0 + BPCHUNK;
    const float* t = gt + (b * NOBJ + n) * 4;
    float tx1 = t[0], ty1 = t[1], tx2 = t[2], ty2 = t[3];
    float ta = (tx2 - tx1) * (ty2 - ty1);
    unsigned long long best = 0ull;
    for (int p = p0 + threadIdx.x; p < p1; p += 256) {
        float4 pr = ((const float4*)priors)[p];
        float px1 = pr.x - pr.z * 0.5f, py1 = pr.y - pr.w * 0.5f;
        float px2 = pr.x + pr.z * 0.5f, py2 = pr.y + pr.w * 0.5f;
        float iw = fmaxf(fminf(tx2, px2) - fmaxf(tx1, px1), 0.f);
        float ih = fmaxf(fminf(ty2, py2) - fmaxf(ty1, py1), 0.f);
        float inter = iw * ih;
        float iou = inter / (ta + (px2 - px1) * (py2 - py1) - inter);
        unsigned long long pk = ((unsigned long long)__float_as_uint(iou) << 32)
                              | (unsigned long long)(0xFFFFFFFFu - (unsigned)p);
        if (pk > best) best = pk;
    }
    __shared__ unsigned long long sb[256];
    int tid = threadIdx.x;
    sb[tid] = best; __syncthreads();
    for (int s = 128; s > 0; s >>= 1) {
        if (tid < s && sb[tid + s] > sb[tid]) sb[tid] = sb[tid + s];
        __syncthreads();
    }
    if (tid == 0) bp8[(b * NOBJ + n) * BPSPLIT + z] = sb[0];
}

// Per prior: best truth (argmax over 20, tie->first), force-match (last gt wins),
// conf_t, and smooth-L1 loc loss for positives. Staging reduces the 8 bp
// slots per (b,n) to the global best prior index.
__global__ void k_match(const float* __restrict__ loc_data,
                        const float* __restrict__ priors,
                        const float* __restrict__ gt,
                        const int* __restrict__ labels,
                        const unsigned long long* __restrict__ bp8,
                        int* __restrict__ conf_t,
                        float* __restrict__ cnt_f,
                        int* __restrict__ cnt_i) {
    int b = blockIdx.y;
    int tid = threadIdx.x;
    int p = blockIdx.x * 256 + tid;
    __shared__ float st[NOBJ][4];
    __shared__ int slab[NOBJ], sbp[NOBJ];
    if (tid < NOBJ * 4) ((float*)st)[tid] = gt[b * NOBJ * 4 + tid];
    if (tid < NOBJ) {
        slab[tid] = labels[b * NOBJ + tid];
        unsigned long long m = 0ull;
        #pragma unroll
        for (int z = 0; z < BPSPLIT; z++) {
            unsigned long long v = bp8[(b * NOBJ + tid) * BPSPLIT + z];
            if (v > m) m = v;
        }
        sbp[tid] = (int)(0xFFFFFFFFu - (unsigned)m);
    }
    __syncthreads();
    float s_l1 = 0.f; int is_pos = 0;
    if (p < PP) {
        float4 pr = ((const float4*)priors)[p];
        float px1 = pr.x - pr.z * 0.5f, py1 = pr.y - pr.w * 0.5f;
        float px2 = pr.x + pr.z * 0.5f, py2 = pr.y + pr.w * 0.5f;
        float pa = (px2 - px1) * (py2 - py1);
        float best = -1.f; int bn = 0;
        for (int n = 0; n < NOBJ; n++) {
            float tx1 = st[n][0], ty1 = st[n][1], tx2 = st[n][2], ty2 = st[n][3];
            float iw = fmaxf(fminf(tx2, px2) - fmaxf(tx1, px1), 0.f);
            float ih = fmaxf(fminf(ty2, py2) - fmaxf(ty1, py1), 0.f);
            float inter = iw * ih;
            float iou = inter / ((tx2 - tx1) * (ty2 - ty1) + pa - inter);
            if (iou > best) { best = iou; bn = n; }  // tie -> first n
        }
        float ov = best;
        for (int n = 0; n < NOBJ; n++)
            if (sbp[n] == p) { bn = n; ov = 2.0f; }  // last n wins
        int conf = slab[bn];
        if (ov < 0.5f) conf = -1;
        if (ov < 0.4f) conf = 0;
        conf_t[b * PP + p] = conf;
        if (conf > 0) {
            is_pos = 1;
            float mx1 = st[bn][0], my1 = st[bn][1], mx2 = st[bn][2], my2 = st[bn][3];
            float gcx = ((mx1 + mx2) * 0.5f - pr.x) / (0.1f * pr.z);
            float gcy = ((my1 + my2) * 0.5f - pr.y) / (0.1f * pr.w);
            float gw = logf((mx2 - mx1) / pr.z) / 0.2f;
            float gh = logf((my2 - my1) / pr.w) / 0.2f;
            float4 ld = ((const float4*)loc_data)[b * PP + p];
            s_l1 = smooth_l1(ld.x - gcx) + smooth_l1(ld.y - gcy) +
                   smooth_l1(ld.z - gw) + smooth_l1(ld.w - gh);
        }
    }
    __shared__ float rs[256]; __shared__ int rc[256];
    rs[tid] = s_l1; rc[tid] = is_pos; __syncthreads();
    for (int s = 128; s > 0; s >>= 1) {
        if (tid < s) { rs[tid] += rs[tid + s]; rc[tid] += rc[tid + s]; }
        __syncthreads();
    }
    if (tid == 0) {
        if (rs[0] != 0.f) atomicAdd(&cnt_f[1], rs[0]);
        if (rc[0])        atomicAdd(&cnt_i[0], rc[0]);
    }
}

// ROW-PER-LANE, NO LDS staging (r12, ~100us) + FUSED level-A histogram:
// per-block 2048-bin LDS hist of key>>21 (LDS atomics), flushed once per
// block to 8 spread global copies (r3/r4-proven pattern; measured free).
__global__ void __launch_bounds__(256) k_conf(const float* __restrict__ conf_data,
                                              const int* __restrict__ conf_t,
                                              unsigned* __restrict__ key,
                                              float* __restrict__ ce,
                                              float* __restrict__ cnt_f,
                                              unsigned* __restrict__ hA) {
    __shared__ unsigned lhist[2048];
    int tid = threadIdx.x;
    for (int j = tid; j < 2048; j += 256) lhist[j] = 0;
    __syncthreads();

    int row = blockIdx.x * 256 + tid;
    bool act = row < ROWS;
    int rr = act ? row : ROWS - 1;
    const float* x = conf_data + (size_t)rr * CC;
    int ct = conf_t[rr];

    float4 v[20];
    #pragma unroll
    for (int j = 0; j < 20; j++) __builtin_memcpy(&v[j], x + 4 * j, 16);
    float x80 = x[80];

    // fg = max over classes 1..80 (4 accumulators for ILP)
    float f0 = v[0].y, f1 = v[0].z, f2 = v[0].w, f3 = x80;
    #pragma unroll
    for (int j = 1; j < 20; j++) {
        f0 = fmaxf(f0, v[j].x);
        f1 = fmaxf(f1, v[j].y);
        f2 = fmaxf(f2, v[j].z);
        f3 = fmaxf(f3, v[j].w);
    }
    float fg = fmaxf(fmaxf(f0, f1), fmaxf(f2, f3));
    float m = fmaxf(fg, v[0].x);

    const float LOG2E = 1.4426950408889634f;
    float e0 = 0.f, e1 = 0.f, e2 = 0.f, e3 = 0.f;
    #pragma unroll
    for (int j = 0; j < 20; j++) {
        e0 += exp2f((v[j].x - m) * LOG2E);
        e1 += exp2f((v[j].y - m) * LOG2E);
        e2 += exp2f((v[j].z - m) * LOG2E);
        e3 += exp2f((v[j].w - m) * LOG2E);
    }
    float e = (e0 + e1) + (e2 + e3) + exp2f((x80 - m) * LOG2E);

    float lse = m + log2f(e) * 0.6931471805599453f;
    int ctc = min(max(ct, 0), CC - 1);
    float xc = x[ctc];               // global re-fetch (L1-hot), not v[ctc]
    float cev = lse - xc;
    if (act) {
        ce[row] = cev;
        unsigned kv = (ct == 0) ? keymap(fg) : 0u;
        key[row] = kv;
        if (ct > 0) atomicAdd(&cnt_f[2], cev);
        if (ct == 0) atomicAdd(&lhist[kv >> 21], 1u);
    }
    __syncthreads();
    unsigned* hmy = hA + (blockIdx.x & 7) * 2048;
    for (int j = tid; j < 2048; j += 256)
        if (lhist[j]) atomicAdd(&hmy[j], lhist[j]);
}

// Fused selection (r13-proven): scan-A (per-block, plain loads on
// prior-kernel hA) -> phase-B hist -> last-block scan+publish -> phase-C
// hist -> last-block scan+publish -> negative-CE sum -> fused final.
// Relaxed agent atomics + vmcnt(0) completion only. 128 co-resident blocks.
__global__ void __launch_bounds__(256) k_sel(const unsigned* __restrict__ key,
                                             const float* __restrict__ ce,
                                             int* __restrict__ cnt_i,
                                             float* __restrict__ cnt_f,
                                             const unsigned* __restrict__ hA,
                                             unsigned* __restrict__ hB,
                                             unsigned* __restrict__ hC,
                                             float* __restrict__ out) {
    __shared__ unsigned lh[2048];
    __shared__ int amLast;
    int tid = threadIdx.x;
    const uint4* k4 = (const uint4*)key;
    int n4 = ROWS / 4;

    unsigned T = 0xFFFFFFFFu; int eqS = 0;
    unsigned Kr = 3u * (unsigned)cnt_i[0];
    bool decided = (Kr == 0);            // no positives: select none
    unsigned prefixA = 0, remB = 0;
    if (!decided) {
        int binA = scan_bins<2048, false>(hA, Kr, &remB);
        if (binA < 0) { T = 0u; eqS = 0; decided = true; }  // select all
        else prefixA = (unsigned)binA;
    }

    if (!decided) {
        // ---- phase B: bits 20:10 within prefixA ----
        for (int j = tid; j < 2048; j += 256) lh[j] = 0;
        __syncthreads();
        for (int r = blockIdx.x * 256 + tid; r < n4; r += gridDim.x * 256) {
            uint4 k = k4[r];
            if ((k.x >> 21) == prefixA) atomicAdd(&lh[(k.x >> 10) & 0x7FFu], 1u);
            if ((k.y >> 21) == prefixA) atomicAdd(&lh[(k.y >> 10) & 0x7FFu], 1u);
            if ((k.z >> 21) == prefixA) atomicAdd(&lh[(k.z >> 10) & 0x7FFu], 1u);
            if ((k.w >> 21) == prefixA) atomicAdd(&lh[(k.w >> 10) & 0x7FFu], 1u);
        }
        __syncthreads();
        {
            unsigned* hmy = hB + (blockIdx.x & 7) * 2048;
            for (int j = tid; j < 2048; j += 256)
                if (lh[j]) atomicAdd(&hmy[j], lh[j]);
        }
        VMEM_DRAIN();
        if (tid == 0)
            amLast = (__hip_atomic_fetch_add((unsigned*)&cnt_i[12], 1u,
                       __ATOMIC_RELAXED, SCOPE_AGENT) == (unsigned)(gridDim.x - 1));
        __syncthreads();
        if (amLast) {
            unsigned remC; int binB = scan_bins<2048, true>(hB, remB, &remC);
            if (binB < 0) { binB = 0; remC = 0; }   // defensive
            if (tid == 0) {
                astore_i(&cnt_i[15], (int)((prefixA << 11) | (unsigned)binB));
                astore_i(&cnt_i[16], (int)remC);
                VMEM_DRAIN();
                astore_i(&cnt_i[14], 1);  // flagB
            }
        }
        if (tid == 0) {
            while (aload_i(&cnt_i[14]) == 0) __builtin_amdgcn_s_sleep(8);
        }
        __syncthreads();
        unsigned prefixAB = (unsigned)aload_i(&cnt_i[15]);
        unsigned KrC = (unsigned)aload_i(&cnt_i[16]);

        // ---- phase C: bits 9:0 within prefixAB ----
        for (int j = tid; j < 1024; j += 256) lh[j] = 0;
        __syncthreads();
        for (int r = blockIdx.x * 256 + tid; r < n4; r += gridDim.x * 256) {
            uint4 k = k4[r];
            if ((k.x >> 10) == prefixAB) atomicAdd(&lh[k.x & 0x3FFu], 1u);
            if ((k.y >> 10) == prefixAB) atomicAdd(&lh[k.y & 0x3FFu], 1u);
            if ((k.z >> 10) == prefixAB) atomicAdd(&lh[k.z & 0x3FFu], 1u);
            if ((k.w >> 10) == prefixAB) atomicAdd(&lh[k.w & 0x3FFu], 1u);
        }
        __syncthreads();
        {
            unsigned* hmy = hC + (blockIdx.x & 7) * 1024;
            for (int j = tid; j < 1024; j += 256)
                if (lh[j]) atomicAdd(&hmy[j], lh[j]);
        }
        VMEM_DRAIN();
        if (tid == 0)
            amLast = (__hip_atomic_fetch_add((unsigned*)&cnt_i[17], 1u,
                       __ATOMIC_RELAXED, SCOPE_AGENT) == (unsigned)(gridDim.x - 1));
        __syncthreads();
        if (amLast) {
            unsigned remD; int binC = scan_bins<1024, true>(hC, KrC, &remD);
            if (binC < 0) { binC = 0; remD = 0; }   // defensive
            if (tid == 0) {
                astore_i(&cnt_i[10], (int)((prefixAB << 10) | (unsigned)binC));
                astore_i(&cnt_i[11], (int)remD);
                VMEM_DRAIN();
                astore_i(&cnt_i[21], 1);  // flagD
            }
        }
        if (tid == 0) {
            while (aload_i(&cnt_i[21]) == 0) __builtin_amdgcn_s_sleep(8);
        }
        __syncthreads();
        T = (unsigned)aload_i(&cnt_i[10]);
        eqS = aload_i(&cnt_i[11]);
    }

    // ---- negative-CE sum over selected (key > T, or == T up to eqS) ----
    float s = 0.f; int c = 0;
    for (int r = blockIdx.x * 256 + tid; r < n4; r += gridDim.x * 256) {
        uint4 k = k4[r];
        #define DO_ONE(comp, idx) { \
            unsigned kk = k.comp; \
            if (kk) { \
                bool selr = false; \
                if (kk > T) selr = true; \
                else if (kk == T) { int slot = atomicAdd(&cnt_i[5], 1); selr = slot < eqS; } \
                if (selr) { s += ce[4 * r + idx]; c++; } \
            } }
        DO_ONE(x, 0) DO_ONE(y, 1) DO_ONE(z, 2) DO_ONE(w, 3)
        #undef DO_ONE
    }
    __shared__ float rs[256]; __shared__ int rc[256];
    rs[tid] = s; rc[tid] = c; __syncthreads();
    for (int st = 128; st > 0; st >>= 1) {
        if (tid < st) { rs[tid] += rs[tid + st]; rc[tid] += rc[tid + st]; }
        __syncthreads();
    }
    if (tid == 0) {
        if (rs[0] != 0.f) atomicAdd(&cnt_f[3], rs[0]);
        if (rc[0])        atomicAdd(&cnt_i[4], rc[0]);
    }
    VMEM_DRAIN();   // my partial sums are at the coherence point
    if (tid == 0 &&
        __hip_atomic_fetch_add((unsigned*)&cnt_i[13], 1u,
            __ATOMIC_RELAXED, SCOPE_AGENT) == (unsigned)(gridDim.x - 1)) {
        int np = aload_i(&cnt_i[0]);
        int nn = aload_i(&cnt_i[4]);
        float f1 = aload_f(&cnt_f[1]);
        float f2 = aload_f(&cnt_f[2]);
        float f3 = aload_f(&cnt_f[3]);
        out[0] = f1 / (float)max(np, 1);
        out[1] = (f2 + f3) / (float)max(np + nn, 1);
    }
}

extern "C" void kernel_launch(void* const* d_in, const int* in_sizes, int n_in,
                              void* d_out, int out_size, void* d_ws, size_t ws_size,
                              hipStream_t stream) {
    const float* loc    = (const float*)d_in[0];
    const float* conf   = (const float*)d_in[1];
    const float* priors = (const float*)d_in[2];
    const float* gt     = (const float*)d_in[3];
    const int*   labels = (const int*)d_in[4];
    float* out = (float*)d_out;
    int*      wi = (int*)d_ws;
    float*    wf = (float*)d_ws;
    unsigned* wu = (unsigned*)d_ws;
    unsigned long long* wbp = (unsigned long long*)(wi + W_BP);

    // no memset: k_best_prior zeroes cnt+hists; bp slots are plain-stored
    k_best_prior<<<dim3(NOBJ, BB, BPSPLIT), 256, 0, stream>>>(priors, gt, wbp, wi);
    k_match<<<dim3((PP + 255) / 256, BB), 256, 0, stream>>>(
        loc, priors, gt, labels, wbp, wi + W_CONF, wf, wi);
    k_conf<<<CONFBLK, 256, 0, stream>>>(conf, wi + W_CONF, wu + W_KEY,
                                        wf + W_CE, wf, wu + W_HA);
    k_sel<<<SELBLK, 256, 0, stream>>>(wu + W_KEY, wf + W_CE, wi, wf,
                                      wu + W_HA, wu + W_HB, wu + W_HC, out);
}